// Round 3
// baseline (1469.387 us; speedup 1.0000x reference)
//
#include <hip/hip_runtime.h>
#include <math.h>

// ---------------------------------------------------------------------------
// Problem dims
//   depth: [32][8][128][80]  -> conv1(1->128,s2)  [256][128][64][40] (fused, LDS only)
//   conv2(128->64,s2) -> [256][64][32][20]
//   conv3(64->64,s2)  -> [256][64][16][10]
//   conv4(64->32,s2)  -> [256][32][8][5]  -> feats 1280 (+3 relpos) = 1283
//   LTC: sensory sums (parallel over B*S), then 8x6 sequential unfolds on 48 units
//   head: mean over S of v[:4] -> *ow+ob -> @[4x2] + hb -> tanh -> [32][2]
// ---------------------------------------------------------------------------

// ---------- K0: weight transpose [OC][IC][3][3] -> [IC][9][OC] ----------
__global__ void k_transpose_w(const float* __restrict__ src, float* __restrict__ dst,
                              int OC, int IC) {
    int idx = blockIdx.x * blockDim.x + threadIdx.x;
    int total = OC * IC * 9;
    if (idx >= total) return;
    int oc = idx / (IC * 9);
    int rem = idx % (IC * 9);
    int ic = rem / 9;
    int k = rem % 9;
    dst[(ic * 9 + k) * OC + oc] = src[idx];
}

// ---------- K2: fused conv1+conv2 ----------
// grid 512 = n*2 + oh-tile; block 320 (16 oh x 20 ow pixels)
__global__ __launch_bounds__(320) void k_conv12(
    const float* __restrict__ depth,   // [256][128][80]
    const float* __restrict__ w1, const float* __restrict__ b1,
    const float* __restrict__ w2T,     // [128][9][64]
    const float* __restrict__ b2,
    float* __restrict__ out)           // [256][64][32][20]
{
    constexpr int IH0 = 128, IW0 = 80;
    constexpr int IH1 = 64, IW1 = 40;
    constexpr int OH = 32, OW = 20, OC = 64;
    constexpr int TH = 16;
    constexpr int DR = 67, DC = 82, DCP = 83;   // depth tile
    constexpr int CR = 33, CC = 42, CCP = 43;   // conv1 tile rows/cols (2*TH+1, IW1+2)
    constexpr int ICB = 4;

    __shared__ float lds_d[DR * DCP];
    __shared__ float lds_c1[ICB * CR * CCP];
    __shared__ float lds_w2[ICB * 9 * OC];
    __shared__ float lds_w1[128 * 9];
    __shared__ float lds_b1[128];

    const int tid = threadIdx.x;
    const int n = blockIdx.x >> 1;
    const int t0 = (blockIdx.x & 1) * TH;

    // stage depth tile (rows 4*t0-3 .. 4*t0+63, cols -1..80) + conv1 weights
    const float* dimg = depth + (size_t)n * IH0 * IW0;
    const int ih0_base = 4 * t0 - 3;
    for (int idx = tid; idx < DR * DC; idx += 320) {
        int r = idx / DC, c = idx % DC;
        int ih = ih0_base + r, iw = c - 1;
        float v = 0.f;
        if (ih >= 0 && ih < IH0 && iw >= 0 && iw < IW0) v = dimg[ih * IW0 + iw];
        lds_d[r * DCP + c] = v;
    }
    for (int idx = tid; idx < 128 * 9; idx += 320) lds_w1[idx] = w1[idx];
    for (int idx = tid; idx < 128; idx += 320) lds_b1[idx] = b1[idx];

    float acc[OC];
#pragma unroll
    for (int i = 0; i < OC; ++i) acc[i] = 0.f;

    const int ohl = tid / OW, ow = tid % OW;

    for (int icb = 0; icb < 128 / ICB; ++icb) {
        const int ic0 = icb * ICB;
        __syncthreads();
        // compute conv1 (relu) for this ic-block into LDS
        for (int idx = tid; idx < ICB * CR * CC; idx += 320) {
            int ic = idx / (CR * CC);
            int rem = idx % (CR * CC);
            int r = rem / CC, c = rem % CC;
            int ih1 = 2 * t0 - 1 + r;  // conv1 output row (incl. conv2 padding)
            int iw1 = c - 1;
            float v = 0.f;
            if (ih1 >= 0 && ih1 < IH1 && iw1 >= 0 && iw1 < IW1) {
                const float* wp = &lds_w1[(ic0 + ic) * 9];
                float s = lds_b1[ic0 + ic];
                int dr = 2 * r;       // depth tile row base: 2*ih1+kh-1 - ih0_base = 2r+kh
                int dc = 2 * c - 2;   // depth tile col base: 2*iw1+kw-1 +1 = 2c-2+kw
#pragma unroll
                for (int kh = 0; kh < 3; ++kh)
#pragma unroll
                    for (int kw = 0; kw < 3; ++kw)
                        s = fmaf(lds_d[(dr + kh) * DCP + (dc + kw)], wp[kh * 3 + kw], s);
                v = fmaxf(s, 0.f);
            }
            lds_c1[(ic * CR + r) * CCP + c] = v;
        }
        // stage conv2 weight tile (contiguous in [ic][k][oc])
        for (int idx = tid; idx < ICB * 9 * OC; idx += 320)
            lds_w2[idx] = w2T[ic0 * 9 * OC + idx];
        __syncthreads();
        // accumulate
        for (int ic = 0; ic < ICB; ++ic) {
            const float* cb = &lds_c1[(ic * CR + 2 * ohl) * CCP + 2 * ow];
            float in9[9];
#pragma unroll
            for (int kh = 0; kh < 3; ++kh)
#pragma unroll
                for (int kw = 0; kw < 3; ++kw)
                    in9[kh * 3 + kw] = cb[kh * CCP + kw];
#pragma unroll
            for (int k = 0; k < 9; ++k) {
                const float4* wq = reinterpret_cast<const float4*>(&lds_w2[(ic * 9 + k) * OC]);
                float iv = in9[k];
#pragma unroll
                for (int q = 0; q < OC / 4; ++q) {
                    float4 wv = wq[q];
                    acc[4 * q + 0] = fmaf(iv, wv.x, acc[4 * q + 0]);
                    acc[4 * q + 1] = fmaf(iv, wv.y, acc[4 * q + 1]);
                    acc[4 * q + 2] = fmaf(iv, wv.z, acc[4 * q + 2]);
                    acc[4 * q + 3] = fmaf(iv, wv.w, acc[4 * q + 3]);
                }
            }
        }
    }
    // epilogue
    const int oh = t0 + ohl;
    float* obase = out + (size_t)n * OC * OH * OW + oh * OW + ow;
#pragma unroll
    for (int oc = 0; oc < OC; ++oc) {
        float v = fmaxf(acc[oc] + b2[oc], 0.f);
        obase[(size_t)oc * OH * OW] = v;
    }
}

// ---------- K3/K4: generic strided conv (3x3, s2, p1), input from global ----------
template <int IC, int OC, int IH, int IW, int ICB, int NTHREADS>
__global__ __launch_bounds__(NTHREADS) void k_conv_s2(
    const float* __restrict__ in,    // [N][IC][IH][IW]
    const float* __restrict__ wT,    // [IC][9][OC]
    const float* __restrict__ bias,
    float* __restrict__ out)         // [N][OC][IH/2][IW/2]
{
    constexpr int OH = IH / 2, OW = IW / 2;
    constexpr int CR = IH + 1;             // rows -1..IH-1
    constexpr int CC = IW + 2, CCP = IW + 3;
    constexpr int NPIX = OH * OW;

    __shared__ float lds_in[ICB * CR * CCP];
    __shared__ float lds_w[ICB * 9 * OC];

    const int tid = threadIdx.x;
    const int n = blockIdx.x;
    const float* ibase = in + (size_t)n * IC * IH * IW;

    float acc[OC];
#pragma unroll
    for (int i = 0; i < OC; ++i) acc[i] = 0.f;

    const int ohl = tid / OW, ow = tid % OW;

    for (int icb = 0; icb < IC / ICB; ++icb) {
        const int ic0 = icb * ICB;
        __syncthreads();
        for (int idx = tid; idx < ICB * CR * CC; idx += NTHREADS) {
            int ic = idx / (CR * CC);
            int rem = idx % (CR * CC);
            int r = rem / CC, c = rem % CC;
            int ih = r - 1, iw = c - 1;
            float v = 0.f;
            if (ih >= 0 && ih < IH && iw >= 0 && iw < IW)
                v = ibase[((size_t)(ic0 + ic) * IH + ih) * IW + iw];
            lds_in[(ic * CR + r) * CCP + c] = v;
        }
        for (int idx = tid; idx < ICB * 9 * OC; idx += NTHREADS)
            lds_w[idx] = wT[ic0 * 9 * OC + idx];
        __syncthreads();
        if (tid < NPIX) {
            for (int ic = 0; ic < ICB; ++ic) {
                const float* cb = &lds_in[(ic * CR + 2 * ohl) * CCP + 2 * ow];
                float in9[9];
#pragma unroll
                for (int kh = 0; kh < 3; ++kh)
#pragma unroll
                    for (int kw = 0; kw < 3; ++kw)
                        in9[kh * 3 + kw] = cb[kh * CCP + kw];
#pragma unroll
                for (int k = 0; k < 9; ++k) {
                    const float4* wq = reinterpret_cast<const float4*>(&lds_w[(ic * 9 + k) * OC]);
                    float iv = in9[k];
#pragma unroll
                    for (int q = 0; q < OC / 4; ++q) {
                        float4 wv = wq[q];
                        acc[4 * q + 0] = fmaf(iv, wv.x, acc[4 * q + 0]);
                        acc[4 * q + 1] = fmaf(iv, wv.y, acc[4 * q + 1]);
                        acc[4 * q + 2] = fmaf(iv, wv.z, acc[4 * q + 2]);
                        acc[4 * q + 3] = fmaf(iv, wv.w, acc[4 * q + 3]);
                    }
                }
            }
        }
    }
    if (tid < NPIX) {
        float* obase = out + (size_t)n * OC * OH * OW + ohl * OW + ow;
#pragma unroll
        for (int oc = 0; oc < OC; ++oc) {
            float v = fmaxf(acc[oc] + bias[oc], 0.f);
            obase[(size_t)oc * OH * OW] = v;
        }
    }
}

// ---------- K5: sensory synapse sums (parallel over B*S) ----------
__global__ __launch_bounds__(256) void k_sensory(
    const float* __restrict__ feats,   // conv4 out, [256][1280] (flat NCHW)
    const float* __restrict__ relpos,  // [256][3]
    const float* __restrict__ smu, const float* __restrict__ ssig,
    const float* __restrict__ sw, const float* __restrict__ sev,
    const float* __restrict__ smask,
    const float* __restrict__ iw, const float* __restrict__ ib,
    float* __restrict__ wns, float* __restrict__ wds)  // [256][48]
{
    constexpr int NS = 1283, U = 48, NG = 5;
    __shared__ float lds_inp[NS];
    __shared__ float lds_pn[NG * U], lds_pd[NG * U];

    const int tid = threadIdx.x;
    const int bs = blockIdx.x;

    for (int f = tid; f < NS; f += 256) {
        float x = (f < 1280) ? feats[(size_t)bs * 1280 + f] : relpos[bs * 3 + (f - 1280)];
        lds_inp[f] = x * iw[f] + ib[f];
    }
    __syncthreads();

    if (tid < NG * U) {
        const int p = tid / U, j = tid % U;
        const int i0 = (NS * p) / NG, i1 = (NS * (p + 1)) / NG;
        float pn = 0.f, pd = 0.f;
        for (int i = i0; i < i1; ++i) {
            float x = lds_inp[i];
            int o = i * U + j;
            float arg = ssig[o] * (x - smu[o]);
            float e = __expf(-arg);
            float r = 1.f / (1.f + e);
            float sact = sw[o] * r * smask[o];
            pn = fmaf(sact, sev[o], pn);
            pd += sact;
        }
        lds_pn[tid] = pn;
        lds_pd[tid] = pd;
    }
    __syncthreads();
    if (tid < U) {
        float sn = 0.f, sd = 0.f;
#pragma unroll
        for (int p = 0; p < NG; ++p) { sn += lds_pn[p * U + tid]; sd += lds_pd[p * U + tid]; }
        wns[bs * U + tid] = sn;
        wds[bs * U + tid] = sd;
    }
}

// ---------- K6: LTC recurrence + head (one block per batch element) ----------
__global__ __launch_bounds__(192) void k_recur(
    const float* __restrict__ wns, const float* __restrict__ wds,   // [32][8][48]
    const float* __restrict__ gleak, const float* __restrict__ vleak,
    const float* __restrict__ cm,
    const float* __restrict__ mu, const float* __restrict__ sigma,
    const float* __restrict__ wsyn, const float* __restrict__ erev,
    const float* __restrict__ mask,
    const float* __restrict__ ow_, const float* __restrict__ ob_,
    const float* __restrict__ hw, const float* __restrict__ hb,
    float* __restrict__ outp)  // [32][2]
{
    constexpr int U = 48, S = 8, NU = 6, P = 4;
    constexpr float LOG2E = 1.44269504088896f;
    __shared__ float A[U * U], Bc[U * U], WE[U * U], WM[U * U];
    __shared__ float vv[U];
    __shared__ float pn[P * U], pd[P * U];
    __shared__ float out4[4];

    const int tid = threadIdx.x;
    const int b = blockIdx.x;
    const int p = tid / U, j = tid % U;

    // fold params: sigmoid(sigma*(v-mu)) = 1/(1+exp2(v*(-sigma*log2e) + sigma*mu*log2e))
    for (int idx = tid; idx < U * U; idx += 192) {
        float sg = sigma[idx], m = mu[idx], w = wsyn[idx] * mask[idx];
        A[idx] = -sg * LOG2E;
        Bc[idx] = sg * m * LOG2E;
        WE[idx] = w * erev[idx];
        WM[idx] = w;
    }
    if (tid < U) vv[tid] = 0.f;
    float cmt = 0.f, gl = 0.f, glvl = 0.f;
    if (tid < U) {
        cmt = cm[tid] * 6.f;   // cm * ode_unfolds
        gl = gleak[tid];
        glvl = gl * vleak[tid];
    }
    float acc_o = 0.f;
    __syncthreads();

    for (int s = 0; s < S; ++s) {
        float wn = 0.f, wd = 0.f;
        if (tid < U) {
            wn = wns[(b * S + s) * U + tid];
            wd = wds[(b * S + s) * U + tid];
        }
        for (int u = 0; u < NU; ++u) {
            float an = 0.f, ad = 0.f;
            const int i0 = p * 12;
#pragma unroll
            for (int ii = 0; ii < 12; ++ii) {
                int i = i0 + ii;
                float vi = vv[i];
                int o = i * U + j;
                float e = exp2f(fmaf(vi, A[o], Bc[o]));
                float r = 1.f / (1.f + e);
                an = fmaf(WE[o], r, an);
                ad = fmaf(WM[o], r, ad);
            }
            pn[tid] = an;
            pd[tid] = ad;
            __syncthreads();
            if (tid < U) {
                float num = fmaf(cmt, vv[tid], glvl) + wn;
                float den = cmt + gl + wd;
#pragma unroll
                for (int q = 0; q < P; ++q) { num += pn[q * U + tid]; den += pd[q * U + tid]; }
                vv[tid] = num / (den + 1e-8f);
            }
            __syncthreads();
        }
        if (tid < 4) acc_o += vv[tid];
    }
    if (tid < 4) out4[tid] = (acc_o * 0.125f) * ow_[tid] + ob_[tid];
    __syncthreads();
    if (tid < 2) {
        float r = hb[tid];
#pragma unroll
        for (int k = 0; k < 4; ++k) r += out4[k] * hw[k * 2 + tid];
        outp[b * 2 + tid] = tanhf(r);
    }
}

// ---------------------------------------------------------------------------
extern "C" void kernel_launch(void* const* d_in, const int* in_sizes, int n_in,
                              void* d_out, int out_size, void* d_ws, size_t ws_size,
                              hipStream_t stream) {
    const float* depth  = (const float*)d_in[0];
    const float* relpos = (const float*)d_in[1];
    const float* w1 = (const float*)d_in[2];
    const float* b1 = (const float*)d_in[3];
    const float* w2 = (const float*)d_in[4];
    const float* b2 = (const float*)d_in[5];
    const float* w3 = (const float*)d_in[6];
    const float* b3 = (const float*)d_in[7];
    const float* w4 = (const float*)d_in[8];
    const float* b4 = (const float*)d_in[9];
    const float* gleak = (const float*)d_in[10];
    const float* vleak = (const float*)d_in[11];
    const float* cm    = (const float*)d_in[12];
    const float* mu    = (const float*)d_in[13];
    const float* sigma = (const float*)d_in[14];
    const float* wsyn  = (const float*)d_in[15];
    const float* erev  = (const float*)d_in[16];
    const float* mask  = (const float*)d_in[17];
    const float* smu   = (const float*)d_in[18];
    const float* ssig  = (const float*)d_in[19];
    const float* sw    = (const float*)d_in[20];
    const float* sev   = (const float*)d_in[21];
    const float* smask = (const float*)d_in[22];
    const float* iw    = (const float*)d_in[23];
    const float* ib    = (const float*)d_in[24];
    const float* ow_   = (const float*)d_in[25];
    const float* ob_   = (const float*)d_in[26];
    const float* hw    = (const float*)d_in[27];
    const float* hb    = (const float*)d_in[28];

    float* ws = (float*)d_ws;
    float* conv2o = ws;                     // 256*64*32*20 = 10,485,760
    float* conv3o = conv2o + 10485760;      // 256*64*16*10 =  2,621,440
    float* conv4o = conv3o + 2621440;       // 256*32*8*5   =    327,680
    float* w2T    = conv4o + 327680;        // 128*9*64     =     73,728
    float* w3T    = w2T + 73728;            // 64*9*64      =     36,864
    float* w4T    = w3T + 36864;            // 64*9*32      =     18,432
    float* wnsb   = w4T + 18432;            // 256*48       =     12,288
    float* wdsb   = wnsb + 12288;           // 256*48       =     12,288

    k_transpose_w<<<dim3((73728 + 255) / 256), dim3(256), 0, stream>>>(w2, w2T, 64, 128);
    k_transpose_w<<<dim3((36864 + 255) / 256), dim3(256), 0, stream>>>(w3, w3T, 64, 64);
    k_transpose_w<<<dim3((18432 + 255) / 256), dim3(256), 0, stream>>>(w4, w4T, 32, 64);

    k_conv12<<<dim3(512), dim3(320), 0, stream>>>(depth, w1, b1, w2T, b2, conv2o);
    k_conv_s2<64, 64, 32, 20, 8, 192><<<dim3(256), dim3(192), 0, stream>>>(conv2o, w3T, b3, conv3o);
    k_conv_s2<64, 32, 16, 10, 16, 64><<<dim3(256), dim3(64), 0, stream>>>(conv3o, w4T, b4, conv4o);

    k_sensory<<<dim3(256), dim3(256), 0, stream>>>(conv4o, relpos, smu, ssig, sw, sev, smask,
                                                   iw, ib, wnsb, wdsb);
    k_recur<<<dim3(32), dim3(192), 0, stream>>>(wnsb, wdsb, gleak, vleak, cm, mu, sigma,
                                                wsyn, erev, mask, ow_, ob_, hw, hb,
                                                (float*)d_out);
}

// Round 4
// 1440.624 us; speedup vs baseline: 1.0200x; 1.0200x over previous
//
#include <hip/hip_runtime.h>
#include <math.h>

// ---------------------------------------------------------------------------
//   depth: [32][8][128][80] -> conv1(1->128,s2) fused into conv2 (LDS only)
//   conv2(128->64,s2) -> [256][64][32][20]
//   conv3(64->64,s2)  -> [256][64][16][10]
//   conv4(64->32,s2)  -> [256][32][8][5] -> feats 1280 (+3 relpos) = 1283
//   LTC sensory (parallel) + 8x6 recurrence + head -> [32][2]
// Thread mapping for convs: thread = Px pixels x 16 OC so FMA:ds_read >= 2:1
// (round-3 counters showed 1px x 64oc was LDS-pipe-bound: VALUBusy 32%).
// ---------------------------------------------------------------------------

__global__ void k_transpose_w(const float* __restrict__ src, float* __restrict__ dst,
                              int OC, int IC) {
    int idx = blockIdx.x * blockDim.x + threadIdx.x;
    int total = OC * IC * 9;
    if (idx >= total) return;
    int oc = idx / (IC * 9);
    int rem = idx % (IC * 9);
    int ic = rem / 9;
    int k = rem % 9;
    dst[(ic * 9 + k) * OC + oc] = src[idx];
}

// ---------- fused conv1+conv2: grid 512 (frame x row-half), block 320 ----------
// thread = 4 px (consecutive ow) x 16 oc
__global__ __launch_bounds__(320) void k_conv12(
    const float* __restrict__ depth,   // [256][128][80]
    const float* __restrict__ w1, const float* __restrict__ b1,
    const float* __restrict__ w2T,     // [128][9][64]
    const float* __restrict__ b2,
    float* __restrict__ out)           // [256][64][32][20]
{
    constexpr int IH0 = 128, IW0 = 80;
    constexpr int IH1 = 64, IW1 = 40;
    constexpr int OH = 32, OW = 20, OC = 64;
    constexpr int TH = 16;
    constexpr int DR = 67, DC = 82, DCP = 83;
    constexpr int CR = 33, CC = 42, CCP = 43;
    constexpr int ICB = 4;

    __shared__ float lds_d[DR * DCP];
    __shared__ float lds_c1[ICB * CR * CCP];
    __shared__ float lds_w2[ICB * 9 * OC];
    __shared__ float lds_w1[128 * 9];
    __shared__ float lds_b1[128];

    const int tid = threadIdx.x;
    const int n = blockIdx.x >> 1;
    const int t0 = (blockIdx.x & 1) * TH;

    const float* dimg = depth + (size_t)n * IH0 * IW0;
    const int ih0_base = 4 * t0 - 3;
    for (int idx = tid; idx < DR * DC; idx += 320) {
        int r = idx / DC, c = idx % DC;
        int ih = ih0_base + r, iw = c - 1;
        float v = 0.f;
        if (ih >= 0 && ih < IH0 && iw >= 0 && iw < IW0) v = dimg[ih * IW0 + iw];
        lds_d[r * DCP + c] = v;
    }
    for (int idx = tid; idx < 128 * 9; idx += 320) lds_w1[idx] = w1[idx];
    for (int idx = tid; idx < 128; idx += 320) lds_b1[idx] = b1[idx];

    float acc[4][16];
#pragma unroll
    for (int p = 0; p < 4; ++p)
#pragma unroll
        for (int e = 0; e < 16; ++e) acc[p][e] = 0.f;

    const int ocg = tid & 3;            // oc = ocg*16 + e
    const int pg = tid >> 2;            // 0..79
    const int oh_l = pg / 5;            // 0..15
    const int ow0 = (pg % 5) * 4;       // 0,4,8,12,16

    for (int icb = 0; icb < 128 / ICB; ++icb) {
        const int ic0 = icb * ICB;
        __syncthreads();
        // conv1 (relu) for this ic-block into LDS
        for (int idx = tid; idx < ICB * CR * CC; idx += 320) {
            int ic = idx / (CR * CC);
            int rem = idx % (CR * CC);
            int r = rem / CC, c = rem % CC;
            int ih1 = 2 * t0 - 1 + r;
            int iw1 = c - 1;
            float v = 0.f;
            if (ih1 >= 0 && ih1 < IH1 && iw1 >= 0 && iw1 < IW1) {
                const float* wp = &lds_w1[(ic0 + ic) * 9];
                float s = lds_b1[ic0 + ic];
                int dr = 2 * r;
                int dc = 2 * c - 2;
#pragma unroll
                for (int kh = 0; kh < 3; ++kh)
#pragma unroll
                    for (int kw = 0; kw < 3; ++kw)
                        s = fmaf(lds_d[(dr + kh) * DCP + (dc + kw)], wp[kh * 3 + kw], s);
                v = fmaxf(s, 0.f);
            }
            lds_c1[(ic * CR + r) * CCP + c] = v;
        }
        for (int idx = tid; idx < ICB * 9 * OC; idx += 320)
            lds_w2[idx] = w2T[ic0 * 9 * OC + idx];
        __syncthreads();

        for (int ic = 0; ic < ICB; ++ic) {
            // 3x9 input patch covers 4 stride-2 pixels
            float patch[3][9];
            const float* cb = &lds_c1[(ic * CR + 2 * oh_l) * CCP + 2 * ow0];
#pragma unroll
            for (int r = 0; r < 3; ++r)
#pragma unroll
                for (int c = 0; c < 9; ++c) patch[r][c] = cb[r * CCP + c];
#pragma unroll
            for (int k = 0; k < 9; ++k) {
                const int kh = k / 3, kw = k % 3;
                float wreg[16];
                const float4* w4 = reinterpret_cast<const float4*>(
                    &lds_w2[(ic * 9 + k) * OC + ocg * 16]);
                *reinterpret_cast<float4*>(&wreg[0]) = w4[0];
                *reinterpret_cast<float4*>(&wreg[4]) = w4[1];
                *reinterpret_cast<float4*>(&wreg[8]) = w4[2];
                *reinterpret_cast<float4*>(&wreg[12]) = w4[3];
#pragma unroll
                for (int p = 0; p < 4; ++p) {
                    float iv = patch[kh][2 * p + kw];
#pragma unroll
                    for (int e = 0; e < 16; ++e)
                        acc[p][e] = fmaf(iv, wreg[e], acc[p][e]);
                }
            }
        }
    }
    // epilogue: float4 stores along ow
    const int oh = t0 + oh_l;
#pragma unroll
    for (int e = 0; e < 16; ++e) {
        const int oc = ocg * 16 + e;
        float bb = b2[oc];
        float4 v;
        v.x = fmaxf(acc[0][e] + bb, 0.f);
        v.y = fmaxf(acc[1][e] + bb, 0.f);
        v.z = fmaxf(acc[2][e] + bb, 0.f);
        v.w = fmaxf(acc[3][e] + bb, 0.f);
        *reinterpret_cast<float4*>(
            &out[(((size_t)n * OC + oc) * OH + oh) * OW + ow0]) = v;
    }
}

// ---------- conv3: grid 512 (frame x row-half), block 160, thread = 2px x 16oc ----------
__global__ __launch_bounds__(160) void k_conv3(
    const float* __restrict__ in,    // [256][64][32][20]
    const float* __restrict__ wT,    // [64][9][64]
    const float* __restrict__ bias,
    float* __restrict__ out)         // [256][64][16][10]
{
    constexpr int IC = 64, OC = 64, IH = 32, IW = 20;
    constexpr int OH = 16, OW = 10, TH = 8;
    constexpr int CR = 17, CC = 22, CCP = 23;
    constexpr int ICB = 8;

    __shared__ float lds_in[ICB * CR * CCP];   // 12.5 KB
    __shared__ float lds_w[ICB * 9 * OC];      // 18.4 KB

    const int tid = threadIdx.x;
    const int n = blockIdx.x >> 1;
    const int h0 = (blockIdx.x & 1) * TH;
    const float* ibase = in + (size_t)n * IC * IH * IW;

    float acc[2][16];
#pragma unroll
    for (int p = 0; p < 2; ++p)
#pragma unroll
        for (int e = 0; e < 16; ++e) acc[p][e] = 0.f;

    const int ocg = tid & 3;
    const int pg = tid >> 2;        // 0..39
    const int oh_l = pg / 5;        // 0..7
    const int ow0 = (pg % 5) * 2;   // 0,2,4,6,8

    for (int icb = 0; icb < IC / ICB; ++icb) {
        const int ic0 = icb * ICB;
        __syncthreads();
        for (int idx = tid; idx < ICB * CR * CC; idx += 160) {
            int ic = idx / (CR * CC);
            int rem = idx % (CR * CC);
            int r = rem / CC, c = rem % CC;
            int ih = 2 * h0 - 1 + r, iw = c - 1;
            float v = 0.f;
            if (ih >= 0 && ih < IH && iw >= 0 && iw < IW)
                v = ibase[((size_t)(ic0 + ic) * IH + ih) * IW + iw];
            lds_in[(ic * CR + r) * CCP + c] = v;
        }
        for (int idx = tid; idx < ICB * 9 * OC; idx += 160)
            lds_w[idx] = wT[ic0 * 9 * OC + idx];
        __syncthreads();

        for (int ic = 0; ic < ICB; ++ic) {
            float patch[3][5];
            const float* cb = &lds_in[(ic * CR + 2 * oh_l) * CCP + 2 * ow0];
#pragma unroll
            for (int r = 0; r < 3; ++r)
#pragma unroll
                for (int c = 0; c < 5; ++c) patch[r][c] = cb[r * CCP + c];
#pragma unroll
            for (int k = 0; k < 9; ++k) {
                const int kh = k / 3, kw = k % 3;
                float wreg[16];
                const float4* w4 = reinterpret_cast<const float4*>(
                    &lds_w[(ic * 9 + k) * OC + ocg * 16]);
                *reinterpret_cast<float4*>(&wreg[0]) = w4[0];
                *reinterpret_cast<float4*>(&wreg[4]) = w4[1];
                *reinterpret_cast<float4*>(&wreg[8]) = w4[2];
                *reinterpret_cast<float4*>(&wreg[12]) = w4[3];
#pragma unroll
                for (int p = 0; p < 2; ++p) {
                    float iv = patch[kh][2 * p + kw];
#pragma unroll
                    for (int e = 0; e < 16; ++e)
                        acc[p][e] = fmaf(iv, wreg[e], acc[p][e]);
                }
            }
        }
    }
    const int oh = h0 + oh_l;
#pragma unroll
    for (int e = 0; e < 16; ++e) {
        const int oc = ocg * 16 + e;
        float bb = bias[oc];
        float2 v;
        v.x = fmaxf(acc[0][e] + bb, 0.f);
        v.y = fmaxf(acc[1][e] + bb, 0.f);
        *reinterpret_cast<float2*>(
            &out[(((size_t)n * OC + oc) * OH + oh) * OW + ow0]) = v;
    }
}

// ---------- conv4: generic strided conv (3x3, s2, p1) ----------
template <int IC, int OC, int IH, int IW, int ICB, int NTHREADS>
__global__ __launch_bounds__(NTHREADS) void k_conv_s2(
    const float* __restrict__ in,    // [N][IC][IH][IW]
    const float* __restrict__ wT,    // [IC][9][OC]
    const float* __restrict__ bias,
    float* __restrict__ out)         // [N][OC][IH/2][IW/2]
{
    constexpr int OH = IH / 2, OW = IW / 2;
    constexpr int CR = IH + 1;
    constexpr int CC = IW + 2, CCP = IW + 3;
    constexpr int NPIX = OH * OW;

    __shared__ float lds_in[ICB * CR * CCP];
    __shared__ float lds_w[ICB * 9 * OC];

    const int tid = threadIdx.x;
    const int n = blockIdx.x;
    const float* ibase = in + (size_t)n * IC * IH * IW;

    float acc[OC];
#pragma unroll
    for (int i = 0; i < OC; ++i) acc[i] = 0.f;

    const int ohl = tid / OW, ow = tid % OW;

    for (int icb = 0; icb < IC / ICB; ++icb) {
        const int ic0 = icb * ICB;
        __syncthreads();
        for (int idx = tid; idx < ICB * CR * CC; idx += NTHREADS) {
            int ic = idx / (CR * CC);
            int rem = idx % (CR * CC);
            int r = rem / CC, c = rem % CC;
            int ih = r - 1, iw = c - 1;
            float v = 0.f;
            if (ih >= 0 && ih < IH && iw >= 0 && iw < IW)
                v = ibase[((size_t)(ic0 + ic) * IH + ih) * IW + iw];
            lds_in[(ic * CR + r) * CCP + c] = v;
        }
        for (int idx = tid; idx < ICB * 9 * OC; idx += NTHREADS)
            lds_w[idx] = wT[ic0 * 9 * OC + idx];
        __syncthreads();
        if (tid < NPIX) {
            for (int ic = 0; ic < ICB; ++ic) {
                const float* cb = &lds_in[(ic * CR + 2 * ohl) * CCP + 2 * ow];
                float in9[9];
#pragma unroll
                for (int kh = 0; kh < 3; ++kh)
#pragma unroll
                    for (int kw = 0; kw < 3; ++kw)
                        in9[kh * 3 + kw] = cb[kh * CCP + kw];
#pragma unroll
                for (int k = 0; k < 9; ++k) {
                    const float4* wq = reinterpret_cast<const float4*>(&lds_w[(ic * 9 + k) * OC]);
                    float iv = in9[k];
#pragma unroll
                    for (int q = 0; q < OC / 4; ++q) {
                        float4 wv = wq[q];
                        acc[4 * q + 0] = fmaf(iv, wv.x, acc[4 * q + 0]);
                        acc[4 * q + 1] = fmaf(iv, wv.y, acc[4 * q + 1]);
                        acc[4 * q + 2] = fmaf(iv, wv.z, acc[4 * q + 2]);
                        acc[4 * q + 3] = fmaf(iv, wv.w, acc[4 * q + 3]);
                    }
                }
            }
        }
    }
    if (tid < NPIX) {
        float* obase = out + (size_t)n * OC * OH * OW + ohl * OW + ow;
#pragma unroll
        for (int oc = 0; oc < OC; ++oc) {
            float v = fmaxf(acc[oc] + bias[oc], 0.f);
            obase[(size_t)oc * OH * OW] = v;
        }
    }
}

// ---------- sensory synapse sums ----------
__global__ __launch_bounds__(256) void k_sensory(
    const float* __restrict__ feats,
    const float* __restrict__ relpos,
    const float* __restrict__ smu, const float* __restrict__ ssig,
    const float* __restrict__ sw, const float* __restrict__ sev,
    const float* __restrict__ smask,
    const float* __restrict__ iw, const float* __restrict__ ib,
    float* __restrict__ wns, float* __restrict__ wds)
{
    constexpr int NS = 1283, U = 48, NG = 5;
    __shared__ float lds_inp[NS];
    __shared__ float lds_pn[NG * U], lds_pd[NG * U];

    const int tid = threadIdx.x;
    const int bs = blockIdx.x;

    for (int f = tid; f < NS; f += 256) {
        float x = (f < 1280) ? feats[(size_t)bs * 1280 + f] : relpos[bs * 3 + (f - 1280)];
        lds_inp[f] = x * iw[f] + ib[f];
    }
    __syncthreads();

    if (tid < NG * U) {
        const int p = tid / U, j = tid % U;
        const int i0 = (NS * p) / NG, i1 = (NS * (p + 1)) / NG;
        float pn = 0.f, pd = 0.f;
        for (int i = i0; i < i1; ++i) {
            float x = lds_inp[i];
            int o = i * U + j;
            float arg = ssig[o] * (x - smu[o]);
            float e = __expf(-arg);
            float r = 1.f / (1.f + e);
            float sact = sw[o] * r * smask[o];
            pn = fmaf(sact, sev[o], pn);
            pd += sact;
        }
        lds_pn[tid] = pn;
        lds_pd[tid] = pd;
    }
    __syncthreads();
    if (tid < U) {
        float sn = 0.f, sd = 0.f;
#pragma unroll
        for (int p = 0; p < NG; ++p) { sn += lds_pn[p * U + tid]; sd += lds_pd[p * U + tid]; }
        wns[bs * U + tid] = sn;
        wds[bs * U + tid] = sd;
    }
}

// ---------- LTC recurrence + head ----------
__global__ __launch_bounds__(192) void k_recur(
    const float* __restrict__ wns, const float* __restrict__ wds,
    const float* __restrict__ gleak, const float* __restrict__ vleak,
    const float* __restrict__ cm,
    const float* __restrict__ mu, const float* __restrict__ sigma,
    const float* __restrict__ wsyn, const float* __restrict__ erev,
    const float* __restrict__ mask,
    const float* __restrict__ ow_, const float* __restrict__ ob_,
    const float* __restrict__ hw, const float* __restrict__ hb,
    float* __restrict__ outp)
{
    constexpr int U = 48, S = 8, NU = 6, P = 4;
    constexpr float LOG2E = 1.44269504088896f;
    __shared__ float A[U * U], Bc[U * U], WE[U * U], WM[U * U];
    __shared__ float vv[U];
    __shared__ float pn[P * U], pd[P * U];
    __shared__ float out4[4];

    const int tid = threadIdx.x;
    const int b = blockIdx.x;
    const int p = tid / U, j = tid % U;

    for (int idx = tid; idx < U * U; idx += 192) {
        float sg = sigma[idx], m = mu[idx], w = wsyn[idx] * mask[idx];
        A[idx] = -sg * LOG2E;
        Bc[idx] = sg * m * LOG2E;
        WE[idx] = w * erev[idx];
        WM[idx] = w;
    }
    if (tid < U) vv[tid] = 0.f;
    float cmt = 0.f, gl = 0.f, glvl = 0.f;
    if (tid < U) {
        cmt = cm[tid] * 6.f;
        gl = gleak[tid];
        glvl = gl * vleak[tid];
    }
    float acc_o = 0.f;
    __syncthreads();

    for (int s = 0; s < S; ++s) {
        float wn = 0.f, wd = 0.f;
        if (tid < U) {
            wn = wns[(b * S + s) * U + tid];
            wd = wds[(b * S + s) * U + tid];
        }
        for (int u = 0; u < NU; ++u) {
            float an = 0.f, ad = 0.f;
            const int i0 = p * 12;
#pragma unroll
            for (int ii = 0; ii < 12; ++ii) {
                int i = i0 + ii;
                float vi = vv[i];
                int o = i * U + j;
                float e = exp2f(fmaf(vi, A[o], Bc[o]));
                float r = 1.f / (1.f + e);
                an = fmaf(WE[o], r, an);
                ad = fmaf(WM[o], r, ad);
            }
            pn[tid] = an;
            pd[tid] = ad;
            __syncthreads();
            if (tid < U) {
                float num = fmaf(cmt, vv[tid], glvl) + wn;
                float den = cmt + gl + wd;
#pragma unroll
                for (int q = 0; q < P; ++q) { num += pn[q * U + tid]; den += pd[q * U + tid]; }
                vv[tid] = num / (den + 1e-8f);
            }
            __syncthreads();
        }
        if (tid < 4) acc_o += vv[tid];
    }
    if (tid < 4) out4[tid] = (acc_o * 0.125f) * ow_[tid] + ob_[tid];
    __syncthreads();
    if (tid < 2) {
        float r = hb[tid];
#pragma unroll
        for (int k = 0; k < 4; ++k) r += out4[k] * hw[k * 2 + tid];
        outp[b * 2 + tid] = tanhf(r);
    }
}

// ---------------------------------------------------------------------------
extern "C" void kernel_launch(void* const* d_in, const int* in_sizes, int n_in,
                              void* d_out, int out_size, void* d_ws, size_t ws_size,
                              hipStream_t stream) {
    const float* depth  = (const float*)d_in[0];
    const float* relpos = (const float*)d_in[1];
    const float* w1 = (const float*)d_in[2];
    const float* b1 = (const float*)d_in[3];
    const float* w2 = (const float*)d_in[4];
    const float* b2 = (const float*)d_in[5];
    const float* w3 = (const float*)d_in[6];
    const float* b3 = (const float*)d_in[7];
    const float* w4 = (const float*)d_in[8];
    const float* b4 = (const float*)d_in[9];
    const float* gleak = (const float*)d_in[10];
    const float* vleak = (const float*)d_in[11];
    const float* cm    = (const float*)d_in[12];
    const float* mu    = (const float*)d_in[13];
    const float* sigma = (const float*)d_in[14];
    const float* wsyn  = (const float*)d_in[15];
    const float* erev  = (const float*)d_in[16];
    const float* mask  = (const float*)d_in[17];
    const float* smu   = (const float*)d_in[18];
    const float* ssig  = (const float*)d_in[19];
    const float* sw    = (const float*)d_in[20];
    const float* sev   = (const float*)d_in[21];
    const float* smask = (const float*)d_in[22];
    const float* iw    = (const float*)d_in[23];
    const float* ib    = (const float*)d_in[24];
    const float* ow_   = (const float*)d_in[25];
    const float* ob_   = (const float*)d_in[26];
    const float* hw    = (const float*)d_in[27];
    const float* hb    = (const float*)d_in[28];

    float* ws = (float*)d_ws;
    float* conv2o = ws;                     // 10,485,760
    float* conv3o = conv2o + 10485760;      //  2,621,440
    float* conv4o = conv3o + 2621440;       //    327,680
    float* w2T    = conv4o + 327680;        //     73,728
    float* w3T    = w2T + 73728;            //     36,864
    float* w4T    = w3T + 36864;            //     18,432
    float* wnsb   = w4T + 18432;            //     12,288
    float* wdsb   = wnsb + 12288;           //     12,288

    k_transpose_w<<<dim3((73728 + 255) / 256), dim3(256), 0, stream>>>(w2, w2T, 64, 128);
    k_transpose_w<<<dim3((36864 + 255) / 256), dim3(256), 0, stream>>>(w3, w3T, 64, 64);
    k_transpose_w<<<dim3((18432 + 255) / 256), dim3(256), 0, stream>>>(w4, w4T, 32, 64);

    k_conv12<<<dim3(512), dim3(320), 0, stream>>>(depth, w1, b1, w2T, b2, conv2o);
    k_conv3<<<dim3(512), dim3(160), 0, stream>>>(conv2o, w3T, b3, conv3o);
    k_conv_s2<64, 32, 16, 10, 16, 128><<<dim3(256), dim3(128), 0, stream>>>(conv3o, w4T, b4, conv4o);

    k_sensory<<<dim3(256), dim3(256), 0, stream>>>(conv4o, relpos, smu, ssig, sw, sev, smask,
                                                   iw, ib, wnsb, wdsb);
    k_recur<<<dim3(32), dim3(192), 0, stream>>>(wnsb, wdsb, gleak, vleak, cm, mu, sigma,
                                                wsyn, erev, mask, ow_, ob_, hw, hb,
                                                (float*)d_out);
}

// Round 7
// 1143.983 us; speedup vs baseline: 1.2844x; 1.2593x over previous
//
#include <hip/hip_runtime.h>
#include <math.h>

// ---------------------------------------------------------------------------
// Architecture (round 5): wave-per-ocg mapping.
//  - Each wave owns a 16-oc slice; weight addresses are wave-uniform ->
//    scalar s_load path (off the per-CU LDS pipe, which round-4 counters
//    showed is the bottleneck: 1.55e8 conflict cycles, VALUBusy 36%).
//  - LDS carries only input patches, float2-vectorized with even strides.
//  - conv1 fused into conv2 (recompute per tile into LDS, 2 cols/item).
// ---------------------------------------------------------------------------

__global__ void k_transpose_w(const float* __restrict__ src, float* __restrict__ dst,
                              int OC, int IC) {
    int idx = blockIdx.x * blockDim.x + threadIdx.x;
    int total = OC * IC * 9;
    if (idx >= total) return;
    int oc = idx / (IC * 9);
    int rem = idx % (IC * 9);
    int ic = rem / 9;
    int k = rem % 9;
    dst[(ic * 9 + k) * OC + oc] = src[idx];
}

// ---------- fused conv1+conv2: grid 512 (frame x row-half), block 256 ----------
// wave -> 16-oc group; lane -> 5 px (one quarter of an ow-row) ; acc[5][16]
__global__ __launch_bounds__(256, 2) void k_conv12(
    const float* __restrict__ depth,   // [256][128][80]
    const float* __restrict__ w1g, const float* __restrict__ b1g,
    const float* __restrict__ w2T,     // [128][9][64]
    const float* __restrict__ b2,
    float* __restrict__ out)           // [256][64][32][20]
{
    constexpr int DR = 67, DC = 82, DCP = 84;   // depth tile (rows 4t0-3.., cols -1..80), even stride
    constexpr int CRR = 33, CCP2 = 44;          // conv1 tile rows 2t0-1.., cols -1..41 (padded even)

    __shared__ float lds_d[DR * DCP];           // 22.5 KB
    __shared__ float lds_c1[2 * CRR * CCP2];    // 11.6 KB

    const int tid = threadIdx.x;
    const int lane = tid & 63;
    const int wv = tid >> 6;
    const int ocg16 = __builtin_amdgcn_readfirstlane(wv) * 16;
    const int n = blockIdx.x >> 1;
    const int t0 = (blockIdx.x & 1) * 16;

    // stage depth tile
    const float* dimg = depth + (size_t)n * 128 * 80;
    const int ih0_base = 4 * t0 - 3;
    for (int idx = tid; idx < DR * DC; idx += 256) {
        int r = idx / DC, c = idx - r * DC;
        int ih = ih0_base + r, iw = c - 1;
        float v = 0.f;
        if (ih >= 0 && ih < 128 && iw >= 0 && iw < 80) v = dimg[ih * 80 + iw];
        lds_d[r * DCP + c] = v;
    }

    float acc[5][16];
#pragma unroll
    for (int p = 0; p < 5; ++p)
#pragma unroll
        for (int e = 0; e < 16; ++e) acc[p][e] = 0.f;

    const int oh_l = lane >> 2;        // 0..15
    const int ow0 = (lane & 3) * 5;    // 0,5,10,15
    const float* __restrict__ wb2 = w2T + ocg16;

    for (int icb = 0; icb < 64; ++icb) {
        const int ic0 = icb * 2;
        // uniform (SGPR) conv1 weights for the 2 ics of this block
        float w1a[9], w1b[9];
#pragma unroll
        for (int k = 0; k < 9; ++k) {
            w1a[k] = w1g[ic0 * 9 + k];
            w1b[k] = w1g[ic0 * 9 + 9 + k];
        }
        const float b1a = b1g[ic0], b1b = b1g[ic0 + 1];

        __syncthreads();
        // conv1 phase: 2 ics x 33 rows x 21 col-pairs = 1386 items
        for (int idx = tid; idx < 1386; idx += 256) {
            const int icl = (idx >= 693) ? 1 : 0;
            const int rem = idx - icl * 693;
            const int r = rem / 21, c2 = rem - r * 21;
            const int ih1 = 2 * t0 - 1 + r;
            float o0 = 0.f, o1 = 0.f;
            if (ih1 >= 0 && ih1 < 64) {
                const float bb = icl ? b1b : b1a;
                float s0 = bb, s1 = bb;
                if (c2 == 0) {
                    // only col 1 valid (col 0 is left padding)
#pragma unroll
                    for (int kh = 0; kh < 3; ++kh) {
                        const float* dp = &lds_d[(2 * r + kh) * DCP];
                        float2 a = *(const float2*)&dp[0];
                        float a2 = dp[2];
                        float wk0 = icl ? w1b[kh * 3 + 0] : w1a[kh * 3 + 0];
                        float wk1 = icl ? w1b[kh * 3 + 1] : w1a[kh * 3 + 1];
                        float wk2 = icl ? w1b[kh * 3 + 2] : w1a[kh * 3 + 2];
                        s1 = fmaf(a.x, wk0, s1);
                        s1 = fmaf(a.y, wk1, s1);
                        s1 = fmaf(a2, wk2, s1);
                    }
                    o1 = fmaxf(s1, 0.f);
                } else {
                    const int cb = 4 * c2 - 2;   // even
#pragma unroll
                    for (int kh = 0; kh < 3; ++kh) {
                        const float* dp = &lds_d[(2 * r + kh) * DCP + cb];
                        float2 a = *(const float2*)&dp[0];
                        float2 b = *(const float2*)&dp[2];
                        float e5 = dp[4];
                        float wk0 = icl ? w1b[kh * 3 + 0] : w1a[kh * 3 + 0];
                        float wk1 = icl ? w1b[kh * 3 + 1] : w1a[kh * 3 + 1];
                        float wk2 = icl ? w1b[kh * 3 + 2] : w1a[kh * 3 + 2];
                        s0 = fmaf(a.x, wk0, s0);
                        s0 = fmaf(a.y, wk1, s0);
                        s0 = fmaf(b.x, wk2, s0);
                        s1 = fmaf(b.x, wk0, s1);
                        s1 = fmaf(b.y, wk1, s1);
                        s1 = fmaf(e5, wk2, s1);
                    }
                    o0 = fmaxf(s0, 0.f);
                    o1 = (c2 <= 19) ? fmaxf(s1, 0.f) : 0.f;
                }
            }
            *(float2*)&lds_c1[(icl * CRR + r) * CCP2 + 2 * c2] = make_float2(o0, o1);
        }
        __syncthreads();

        // conv2 accumulate (weights via wave-uniform scalar loads)
#pragma unroll
        for (int icl = 0; icl < 2; ++icl) {
            float patch[3][11];
#pragma unroll
            for (int rr = 0; rr < 3; ++rr) {
                const float* cp = &lds_c1[(icl * CRR + 2 * oh_l + rr) * CCP2 + 2 * ow0];
                float2 v0 = *(const float2*)&cp[0];
                float2 v1 = *(const float2*)&cp[2];
                float2 v2 = *(const float2*)&cp[4];
                float2 v3 = *(const float2*)&cp[6];
                float2 v4 = *(const float2*)&cp[8];
                patch[rr][0] = v0.x; patch[rr][1] = v0.y;
                patch[rr][2] = v1.x; patch[rr][3] = v1.y;
                patch[rr][4] = v2.x; patch[rr][5] = v2.y;
                patch[rr][6] = v3.x; patch[rr][7] = v3.y;
                patch[rr][8] = v4.x; patch[rr][9] = v4.y;
                patch[rr][10] = cp[10];
            }
            const float* __restrict__ wk = wb2 + (size_t)(ic0 + icl) * 576;
#pragma unroll
            for (int k = 0; k < 9; ++k) {
                const int kh = k / 3, kw = k - kh * 3;
#pragma unroll
                for (int e = 0; e < 16; ++e) {
                    const float w = wk[k * 64 + e];
#pragma unroll
                    for (int p = 0; p < 5; ++p)
                        acc[p][e] = fmaf(patch[kh][2 * p + kw], w, acc[p][e]);
                }
            }
        }
    }

    // epilogue
    const int oh = t0 + oh_l;
#pragma unroll
    for (int e = 0; e < 16; ++e) {
        const int oc = ocg16 + e;
        const float bb = b2[oc];
        float* ob = &out[(((size_t)n * 64 + oc) * 32 + oh) * 20 + ow0];
#pragma unroll
        for (int p = 0; p < 5; ++p) ob[p] = fmaxf(acc[p][e] + bb, 0.f);
    }
}

// ---------- conv3: grid 256 (frame), block 256; wave -> ocg; lane -> 2 px-pairs ----------
__device__ __forceinline__ void conv3_accum(
    float (&acc)[2][16], const float* lds_in, int icl, int oh, int owp,
    const float* __restrict__ wk)
{
    float patch[3][5];
#pragma unroll
    for (int rr = 0; rr < 3; ++rr) {
        const float* cp = &lds_in[(icl * 34 + 2 * oh + rr) * 24 + 4 * owp];
        float2 a = *(const float2*)&cp[0];
        float2 b = *(const float2*)&cp[2];
        patch[rr][0] = a.x; patch[rr][1] = a.y;
        patch[rr][2] = b.x; patch[rr][3] = b.y;
        patch[rr][4] = cp[4];
    }
#pragma unroll
    for (int k = 0; k < 9; ++k) {
        const int kh = k / 3, kw = k - kh * 3;
#pragma unroll
        for (int e = 0; e < 16; ++e) {
            const float w = wk[k * 64 + e];
            acc[0][e] = fmaf(patch[kh][kw], w, acc[0][e]);
            acc[1][e] = fmaf(patch[kh][2 + kw], w, acc[1][e]);
        }
    }
}

__global__ __launch_bounds__(256, 2) void k_conv3(
    const float* __restrict__ in,    // [256][64][32][20]
    const float* __restrict__ w3T,   // [64][9][64]
    const float* __restrict__ bias,
    float* __restrict__ out)         // [256][64][16][10]
{
    constexpr int IC = 64, IH = 32, IW = 20;
    constexpr int CR = 34, CC = 22, CCP = 24, ICB = 4;
    __shared__ float lds_in[ICB * CR * CCP];   // 12.75 KB

    const int tid = threadIdx.x;
    const int lane = tid & 63;
    const int wv = tid >> 6;
    const int ocg16 = __builtin_amdgcn_readfirstlane(wv) * 16;
    const int n = blockIdx.x;
    const float* ibase = in + (size_t)n * IC * IH * IW;

    float acc[2][2][16];
#pragma unroll
    for (int q = 0; q < 2; ++q)
#pragma unroll
        for (int p = 0; p < 2; ++p)
#pragma unroll
            for (int e = 0; e < 16; ++e) acc[q][p][e] = 0.f;

    const int oh1 = lane / 5, owp1 = lane - oh1 * 5;        // q = lane (0..63)
    const int q2i = 64 + lane;
    const int oh2 = q2i / 5, owp2 = q2i - oh2 * 5;          // q = 64..79 (lane<16)

    for (int icb = 0; icb < IC / ICB; ++icb) {
        const int ic0 = icb * ICB;
        __syncthreads();
        for (int idx = tid; idx < ICB * CR * CC; idx += 256) {
            int icl = idx / (CR * CC);
            int rem = idx - icl * (CR * CC);
            int r = rem / CC, c = rem - r * CC;
            int ih = r - 1, iw = c - 1;
            float v = 0.f;
            if (ih >= 0 && ih < IH && iw >= 0 && iw < IW)
                v = ibase[((size_t)(ic0 + icl) * IH + ih) * IW + iw];
            lds_in[(icl * CR + r) * CCP + c] = v;
        }
        __syncthreads();
#pragma unroll
        for (int icl = 0; icl < ICB; ++icl) {
            const float* __restrict__ wk = w3T + (size_t)(ic0 + icl) * 576 + ocg16;
            conv3_accum(acc[0], lds_in, icl, oh1, owp1, wk);
            if (lane < 16) conv3_accum(acc[1], lds_in, icl, oh2, owp2, wk);
        }
    }

#pragma unroll
    for (int e = 0; e < 16; ++e) {
        const int oc = ocg16 + e;
        const float bb = bias[oc];
        float2 r0;
        r0.x = fmaxf(acc[0][0][e] + bb, 0.f);
        r0.y = fmaxf(acc[0][1][e] + bb, 0.f);
        *(float2*)&out[((size_t)n * 64 + oc) * 160 + oh1 * 10 + 2 * owp1] = r0;
        if (lane < 16) {
            float2 r1;
            r1.x = fmaxf(acc[1][0][e] + bb, 0.f);
            r1.y = fmaxf(acc[1][1][e] + bb, 0.f);
            *(float2*)&out[((size_t)n * 64 + oc) * 160 + oh2 * 10 + 2 * owp2] = r1;
        }
    }
}

// ---------- conv4: grid 256 (frame), block 128; wave -> ocg(2); lane -> 1 px ----------
__global__ __launch_bounds__(128, 2) void k_conv4(
    const float* __restrict__ in,    // [256][64][16][10]
    const float* __restrict__ w4T,   // [64][9][32]
    const float* __restrict__ bias,  // 32
    float* __restrict__ out)         // [256][32][8][5]
{
    constexpr int IC = 64, IH = 16, IW = 10;
    constexpr int CR = 17, CC = 12, CCP = 12, ICB = 16;
    __shared__ float lds_in[ICB * CR * CCP];   // 12.75 KB

    const int tid = threadIdx.x;
    const int lane = tid & 63;
    const int wv = tid >> 6;
    const int ocg16 = __builtin_amdgcn_readfirstlane(wv) * 16;
    const int n = blockIdx.x;
    const float* ibase = in + (size_t)n * IC * IH * IW;

    float acc[16];
#pragma unroll
    for (int e = 0; e < 16; ++e) acc[e] = 0.f;

    const int oh = lane / 5, ow = lane - oh * 5;   // valid for lane<40

    for (int icb = 0; icb < IC / ICB; ++icb) {
        const int ic0 = icb * ICB;
        __syncthreads();
        for (int idx = tid; idx < ICB * CR * CC; idx += 128) {
            int icl = idx / (CR * CC);
            int rem = idx - icl * (CR * CC);
            int r = rem / CC, c = rem - r * CC;
            int ih = r - 1, iw = c - 1;
            float v = 0.f;
            if (ih >= 0 && ih < IH && iw >= 0 && iw < IW)
                v = ibase[((size_t)(ic0 + icl) * IH + ih) * IW + iw];
            lds_in[(icl * CR + r) * CCP + c] = v;
        }
        __syncthreads();
        if (lane < 40) {
#pragma unroll
            for (int icl = 0; icl < ICB; ++icl) {
                float patch[3][3];
#pragma unroll
                for (int rr = 0; rr < 3; ++rr) {
                    const float* cp = &lds_in[(icl * CR + 2 * oh + rr) * CCP + 2 * ow];
                    float2 a = *(const float2*)&cp[0];
                    patch[rr][0] = a.x; patch[rr][1] = a.y; patch[rr][2] = cp[2];
                }
                const float* __restrict__ wk = w4T + (size_t)(ic0 + icl) * 288 + ocg16;
#pragma unroll
                for (int k = 0; k < 9; ++k) {
                    const int kh = k / 3, kw = k - kh * 3;
#pragma unroll
                    for (int e = 0; e < 16; ++e)
                        acc[e] = fmaf(patch[kh][kw], wk[k * 32 + e], acc[e]);
                }
            }
        }
    }
    if (lane < 40) {
#pragma unroll
        for (int e = 0; e < 16; ++e) {
            const int oc = ocg16 + e;
            out[((size_t)n * 32 + oc) * 40 + oh * 5 + ow] = fmaxf(acc[e] + bias[oc], 0.f);
        }
    }
}

// ---------- sensory synapse sums ----------
__global__ __launch_bounds__(256) void k_sensory(
    const float* __restrict__ feats,
    const float* __restrict__ relpos,
    const float* __restrict__ smu, const float* __restrict__ ssig,
    const float* __restrict__ sw, const float* __restrict__ sev,
    const float* __restrict__ smask,
    const float* __restrict__ iw, const float* __restrict__ ib,
    float* __restrict__ wns, float* __restrict__ wds)
{
    constexpr int NS = 1283, U = 48, NG = 5;
    __shared__ float lds_inp[NS];
    __shared__ float lds_pn[NG * U], lds_pd[NG * U];

    const int tid = threadIdx.x;
    const int bs = blockIdx.x;

    for (int f = tid; f < NS; f += 256) {
        float x = (f < 1280) ? feats[(size_t)bs * 1280 + f] : relpos[bs * 3 + (f - 1280)];
        lds_inp[f] = x * iw[f] + ib[f];
    }
    __syncthreads();

    if (tid < NG * U) {
        const int p = tid / U, j = tid % U;
        const int i0 = (NS * p) / NG, i1 = (NS * (p + 1)) / NG;
        float pn = 0.f, pd = 0.f;
        for (int i = i0; i < i1; ++i) {
            float x = lds_inp[i];
            int o = i * U + j;
            float arg = ssig[o] * (x - smu[o]);
            float e = __expf(-arg);
            float r = 1.f / (1.f + e);
            float sact = sw[o] * r * smask[o];
            pn = fmaf(sact, sev[o], pn);
            pd += sact;
        }
        lds_pn[tid] = pn;
        lds_pd[tid] = pd;
    }
    __syncthreads();
    if (tid < U) {
        float sn = 0.f, sd = 0.f;
#pragma unroll
        for (int p = 0; p < NG; ++p) { sn += lds_pn[p * U + tid]; sd += lds_pd[p * U + tid]; }
        wns[bs * U + tid] = sn;
        wds[bs * U + tid] = sd;
    }
}

// ---------- LTC recurrence + head ----------
__global__ __launch_bounds__(192) void k_recur(
    const float* __restrict__ wns, const float* __restrict__ wds,
    const float* __restrict__ gleak, const float* __restrict__ vleak,
    const float* __restrict__ cm,
    const float* __restrict__ mu, const float* __restrict__ sigma,
    const float* __restrict__ wsyn, const float* __restrict__ erev,
    const float* __restrict__ mask,
    const float* __restrict__ ow_, const float* __restrict__ ob_,
    const float* __restrict__ hw, const float* __restrict__ hb,
    float* __restrict__ outp)
{
    constexpr int U = 48, S = 8, NU = 6, P = 4;
    constexpr float LOG2E = 1.44269504088896f;
    __shared__ float A[U * U], Bc[U * U], WE[U * U], WM[U * U];
    __shared__ float vv[U];
    __shared__ float pn[P * U], pd[P * U];
    __shared__ float out4[4];

    const int tid = threadIdx.x;
    const int b = blockIdx.x;
    const int p = tid / U, j = tid % U;

    for (int idx = tid; idx < U * U; idx += 192) {
        float sg = sigma[idx], m = mu[idx], w = wsyn[idx] * mask[idx];
        A[idx] = -sg * LOG2E;
        Bc[idx] = sg * m * LOG2E;
        WE[idx] = w * erev[idx];
        WM[idx] = w;
    }
    if (tid < U) vv[tid] = 0.f;
    float cmt = 0.f, gl = 0.f, glvl = 0.f;
    if (tid < U) {
        cmt = cm[tid] * 6.f;
        gl = gleak[tid];
        glvl = gl * vleak[tid];
    }
    float acc_o = 0.f;
    __syncthreads();

    for (int s = 0; s < S; ++s) {
        float wn = 0.f, wd = 0.f;
        if (tid < U) {
            wn = wns[(b * S + s) * U + tid];
            wd = wds[(b * S + s) * U + tid];
        }
        for (int u = 0; u < NU; ++u) {
            float an = 0.f, ad = 0.f;
            const int i0 = p * 12;
#pragma unroll
            for (int ii = 0; ii < 12; ++ii) {
                int i = i0 + ii;
                float vi = vv[i];
                int o = i * U + j;
                float e = exp2f(fmaf(vi, A[o], Bc[o]));
                float r = 1.f / (1.f + e);
                an = fmaf(WE[o], r, an);
                ad = fmaf(WM[o], r, ad);
            }
            pn[tid] = an;
            pd[tid] = ad;
            __syncthreads();
            if (tid < U) {
                float num = fmaf(cmt, vv[tid], glvl) + wn;
                float den = cmt + gl + wd;
#pragma unroll
                for (int q = 0; q < P; ++q) { num += pn[q * U + tid]; den += pd[q * U + tid]; }
                vv[tid] = num / (den + 1e-8f);
            }
            __syncthreads();
        }
        if (tid < 4) acc_o += vv[tid];
    }
    if (tid < 4) out4[tid] = (acc_o * 0.125f) * ow_[tid] + ob_[tid];
    __syncthreads();
    if (tid < 2) {
        float r = hb[tid];
#pragma unroll
        for (int k = 0; k < 4; ++k) r += out4[k] * hw[k * 2 + tid];
        outp[b * 2 + tid] = tanhf(r);
    }
}

// ---------------------------------------------------------------------------
extern "C" void kernel_launch(void* const* d_in, const int* in_sizes, int n_in,
                              void* d_out, int out_size, void* d_ws, size_t ws_size,
                              hipStream_t stream) {
    const float* depth  = (const float*)d_in[0];
    const float* relpos = (const float*)d_in[1];
    const float* w1 = (const float*)d_in[2];
    const float* b1 = (const float*)d_in[3];
    const float* w2 = (const float*)d_in[4];
    const float* b2 = (const float*)d_in[5];
    const float* w3 = (const float*)d_in[6];
    const float* b3 = (const float*)d_in[7];
    const float* w4 = (const float*)d_in[8];
    const float* b4 = (const float*)d_in[9];
    const float* gleak = (const float*)d_in[10];
    const float* vleak = (const float*)d_in[11];
    const float* cm    = (const float*)d_in[12];
    const float* mu    = (const float*)d_in[13];
    const float* sigma = (const float*)d_in[14];
    const float* wsyn  = (const float*)d_in[15];
    const float* erev  = (const float*)d_in[16];
    const float* mask  = (const float*)d_in[17];
    const float* smu   = (const float*)d_in[18];
    const float* ssig  = (const float*)d_in[19];
    const float* sw    = (const float*)d_in[20];
    const float* sev   = (const float*)d_in[21];
    const float* smask = (const float*)d_in[22];
    const float* iw    = (const float*)d_in[23];
    const float* ib    = (const float*)d_in[24];
    const float* ow_   = (const float*)d_in[25];
    const float* ob_   = (const float*)d_in[26];
    const float* hw    = (const float*)d_in[27];
    const float* hb    = (const float*)d_in[28];

    float* ws = (float*)d_ws;
    float* conv2o = ws;                     // 10,485,760
    float* conv3o = conv2o + 10485760;      //  2,621,440
    float* conv4o = conv3o + 2621440;       //    327,680
    float* w2T    = conv4o + 327680;        //     73,728
    float* w3T    = w2T + 73728;            //     36,864
    float* w4T    = w3T + 36864;            //     18,432
    float* wnsb   = w4T + 18432;            //     12,288
    float* wdsb   = wnsb + 12288;           //     12,288

    k_transpose_w<<<dim3((73728 + 255) / 256), dim3(256), 0, stream>>>(w2, w2T, 64, 128);
    k_transpose_w<<<dim3((36864 + 255) / 256), dim3(256), 0, stream>>>(w3, w3T, 64, 64);
    k_transpose_w<<<dim3((18432 + 255) / 256), dim3(256), 0, stream>>>(w4, w4T, 32, 64);

    k_conv12<<<dim3(512), dim3(256), 0, stream>>>(depth, w1, b1, w2T, b2, conv2o);
    k_conv3<<<dim3(256), dim3(256), 0, stream>>>(conv2o, w3T, b3, conv3o);
    k_conv4<<<dim3(256), dim3(128), 0, stream>>>(conv3o, w4T, b4, conv4o);

    k_sensory<<<dim3(256), dim3(256), 0, stream>>>(conv4o, relpos, smu, ssig, sw, sev, smask,
                                                   iw, ib, wnsb, wdsb);
    k_recur<<<dim3(32), dim3(192), 0, stream>>>(wnsb, wdsb, gleak, vleak, cm, mu, sigma,
                                                wsyn, erev, mask, ow_, ob_, hw, hb,
                                                (float*)d_out);
}

// Round 9
// 876.858 us; speedup vs baseline: 1.6757x; 1.3046x over previous
//
#include <hip/hip_runtime.h>
#include <math.h>

// ---------------------------------------------------------------------------
// Round 8:
//  - conv12: ICB=4 (32 barrier rounds, was 64), conv1-tile stride 46 (was 44:
//    stride-88 rows put oh_l{0,4,8,12} in one bank -> 4-way conflict, 4.5e7 cyc)
//  - conv3: block 512 (8 waves = 2/SIMD; was 256 = 1/SIMD, latency-exposed),
//    wave=(ocg,row-half), lane -> 40 px-pairs, CCP 26
//  - conv4 fused into sensory kernel (1 wave/SIMD conv4 kernel + global
//    round-trip + w4T transpose deleted)
// Weights stay on the scalar path (wave-uniform addresses -> s_load).
// ---------------------------------------------------------------------------

__global__ void k_transpose_w(const float* __restrict__ src, float* __restrict__ dst,
                              int OC, int IC) {
    int idx = blockIdx.x * blockDim.x + threadIdx.x;
    int total = OC * IC * 9;
    if (idx >= total) return;
    int oc = idx / (IC * 9);
    int rem = idx % (IC * 9);
    int ic = rem / 9;
    int k = rem % 9;
    dst[(ic * 9 + k) * OC + oc] = src[idx];
}

// ---------- fused conv1+conv2: grid 512 (frame x row-half), block 256 ----------
__global__ __launch_bounds__(256, 2) void k_conv12(
    const float* __restrict__ depth,   // [256][128][80]
    const float* __restrict__ w1g, const float* __restrict__ b1g,
    const float* __restrict__ w2T,     // [128][9][64]
    const float* __restrict__ b2,
    float* __restrict__ out)           // [256][64][32][20]
{
    constexpr int DR = 67, DC = 82, DCP = 84;
    constexpr int CRR = 33, CCP2 = 46;          // 46: row-pair stride 92 = 28 mod 32
    constexpr int ICB = 4;

    __shared__ float lds_d[DR * DCP];           // 22.5 KB
    __shared__ float lds_c1[ICB * CRR * CCP2];  // 24.3 KB

    const int tid = threadIdx.x;
    const int lane = tid & 63;
    const int wv = tid >> 6;
    const int ocg16 = __builtin_amdgcn_readfirstlane(wv) * 16;
    const int n = blockIdx.x >> 1;
    const int t0 = (blockIdx.x & 1) * 16;

    const float* dimg = depth + (size_t)n * 128 * 80;
    const int ih0_base = 4 * t0 - 3;
    for (int idx = tid; idx < DR * DC; idx += 256) {
        int r = idx / DC, c = idx - r * DC;
        int ih = ih0_base + r, iw = c - 1;
        float v = 0.f;
        if (ih >= 0 && ih < 128 && iw >= 0 && iw < 80) v = dimg[ih * 80 + iw];
        lds_d[r * DCP + c] = v;
    }

    float acc[5][16];
#pragma unroll
    for (int p = 0; p < 5; ++p)
#pragma unroll
        for (int e = 0; e < 16; ++e) acc[p][e] = 0.f;

    const int oh_l = lane >> 2;
    const int ow0 = (lane & 3) * 5;
    const float* __restrict__ wb2 = w2T + ocg16;

    for (int icb = 0; icb < 128 / ICB; ++icb) {
        const int ic0 = icb * ICB;
        // uniform conv1 weights for the 4 ics (static-indexed -> SGPRs)
        float w1q[ICB][9], b1q[ICB];
#pragma unroll
        for (int icl = 0; icl < ICB; ++icl) {
#pragma unroll
            for (int k = 0; k < 9; ++k) w1q[icl][k] = w1g[(ic0 + icl) * 9 + k];
            b1q[icl] = b1g[ic0 + icl];
        }

        __syncthreads();
        // conv1 phase: per icl, 33 rows x 21 col-pairs = 693 items
#pragma unroll
        for (int icl = 0; icl < ICB; ++icl) {
            for (int idx = tid; idx < 693; idx += 256) {
                const int r = idx / 21, c2 = idx - r * 21;
                const int ih1 = 2 * t0 - 1 + r;
                float o0 = 0.f, o1 = 0.f;
                if (ih1 >= 0 && ih1 < 64) {
                    float s0 = b1q[icl], s1 = s0;
                    if (c2 == 0) {
#pragma unroll
                        for (int kh = 0; kh < 3; ++kh) {
                            const float* dp = &lds_d[(2 * r + kh) * DCP];
                            float2 a = *(const float2*)&dp[0];
                            float a2 = dp[2];
                            s1 = fmaf(a.x, w1q[icl][kh * 3 + 0], s1);
                            s1 = fmaf(a.y, w1q[icl][kh * 3 + 1], s1);
                            s1 = fmaf(a2, w1q[icl][kh * 3 + 2], s1);
                        }
                        o1 = fmaxf(s1, 0.f);
                    } else {
                        const int cb = 4 * c2 - 2;
#pragma unroll
                        for (int kh = 0; kh < 3; ++kh) {
                            const float* dp = &lds_d[(2 * r + kh) * DCP + cb];
                            float2 a = *(const float2*)&dp[0];
                            float2 b = *(const float2*)&dp[2];
                            float e5 = dp[4];
                            s0 = fmaf(a.x, w1q[icl][kh * 3 + 0], s0);
                            s0 = fmaf(a.y, w1q[icl][kh * 3 + 1], s0);
                            s0 = fmaf(b.x, w1q[icl][kh * 3 + 2], s0);
                            s1 = fmaf(b.x, w1q[icl][kh * 3 + 0], s1);
                            s1 = fmaf(b.y, w1q[icl][kh * 3 + 1], s1);
                            s1 = fmaf(e5, w1q[icl][kh * 3 + 2], s1);
                        }
                        o0 = fmaxf(s0, 0.f);
                        o1 = (c2 <= 19) ? fmaxf(s1, 0.f) : 0.f;
                    }
                }
                *(float2*)&lds_c1[(icl * CRR + r) * CCP2 + 2 * c2] = make_float2(o0, o1);
            }
        }
        __syncthreads();

        // conv2 accumulate
#pragma unroll
        for (int icl = 0; icl < ICB; ++icl) {
            float patch[3][11];
#pragma unroll
            for (int rr = 0; rr < 3; ++rr) {
                const float* cp = &lds_c1[(icl * CRR + 2 * oh_l + rr) * CCP2 + 2 * ow0];
                float2 v0 = *(const float2*)&cp[0];
                float2 v1 = *(const float2*)&cp[2];
                float2 v2 = *(const float2*)&cp[4];
                float2 v3 = *(const float2*)&cp[6];
                float2 v4 = *(const float2*)&cp[8];
                patch[rr][0] = v0.x; patch[rr][1] = v0.y;
                patch[rr][2] = v1.x; patch[rr][3] = v1.y;
                patch[rr][4] = v2.x; patch[rr][5] = v2.y;
                patch[rr][6] = v3.x; patch[rr][7] = v3.y;
                patch[rr][8] = v4.x; patch[rr][9] = v4.y;
                patch[rr][10] = cp[10];
            }
            const float* __restrict__ wk = wb2 + (size_t)(ic0 + icl) * 576;
#pragma unroll
            for (int k = 0; k < 9; ++k) {
                const int kh = k / 3, kw = k - kh * 3;
                float wreg[16];
                const float4 wA = *(const float4*)(wk + k * 64);
                const float4 wB = *(const float4*)(wk + k * 64 + 4);
                const float4 wC = *(const float4*)(wk + k * 64 + 8);
                const float4 wD = *(const float4*)(wk + k * 64 + 12);
                wreg[0] = wA.x; wreg[1] = wA.y; wreg[2] = wA.z; wreg[3] = wA.w;
                wreg[4] = wB.x; wreg[5] = wB.y; wreg[6] = wB.z; wreg[7] = wB.w;
                wreg[8] = wC.x; wreg[9] = wC.y; wreg[10] = wC.z; wreg[11] = wC.w;
                wreg[12] = wD.x; wreg[13] = wD.y; wreg[14] = wD.z; wreg[15] = wD.w;
#pragma unroll
                for (int e = 0; e < 16; ++e) {
#pragma unroll
                    for (int p = 0; p < 5; ++p)
                        acc[p][e] = fmaf(patch[kh][2 * p + kw], wreg[e], acc[p][e]);
                }
            }
        }
    }

    const int oh = t0 + oh_l;
#pragma unroll
    for (int e = 0; e < 16; ++e) {
        const int oc = ocg16 + e;
        const float bb = b2[oc];
        float* ob = &out[(((size_t)n * 64 + oc) * 32 + oh) * 20 + ow0];
#pragma unroll
        for (int p = 0; p < 5; ++p) ob[p] = fmaxf(acc[p][e] + bb, 0.f);
    }
}

// ---------- conv3: grid 256 (frame), block 512 (8 waves = 2/SIMD) ----------
// wave -> (ocg16, row-half); lane < 40 -> (oh_l 0..7, owp 0..4) px-pair
__global__ __launch_bounds__(512, 2) void k_conv3(
    const float* __restrict__ in,    // [256][64][32][20]
    const float* __restrict__ w3T,   // [64][9][64]
    const float* __restrict__ bias,
    float* __restrict__ out)         // [256][64][16][10]
{
    constexpr int IC = 64, IH = 32, IW = 20;
    constexpr int CR = 33, CC = 22, CCP = 26, ICB = 8;
    __shared__ float lds_in[ICB * CR * CCP];   // 27.5 KB

    const int tid = threadIdx.x;
    const int lane = tid & 63;
    const int wv = tid >> 6;
    const int ocg16 = __builtin_amdgcn_readfirstlane(wv >> 1) * 16;
    const int half = __builtin_amdgcn_readfirstlane(wv & 1);
    const int n = blockIdx.x;
    const float* ibase = in + (size_t)n * IC * IH * IW;

    float acc[2][16];
#pragma unroll
    for (int p = 0; p < 2; ++p)
#pragma unroll
        for (int e = 0; e < 16; ++e) acc[p][e] = 0.f;

    const int oh_l = lane / 5, owp = lane - oh_l * 5;   // valid lane<40
    const int oh_g = half * 8 + oh_l;

    for (int icb = 0; icb < IC / ICB; ++icb) {
        const int ic0 = icb * ICB;
        __syncthreads();
        for (int idx = tid; idx < ICB * CR * CC; idx += 512) {
            int icl = idx / (CR * CC);
            int rem = idx - icl * (CR * CC);
            int r = rem / CC, c = rem - r * CC;
            int ih = r - 1, iw = c - 1;
            float v = 0.f;
            if (ih >= 0 && ih < IH && iw >= 0 && iw < IW)
                v = ibase[((size_t)(ic0 + icl) * IH + ih) * IW + iw];
            lds_in[(icl * CR + r) * CCP + c] = v;
        }
        __syncthreads();
        if (lane < 40) {
#pragma unroll
            for (int icl = 0; icl < ICB; ++icl) {
                float patch[3][5];
#pragma unroll
                for (int rr = 0; rr < 3; ++rr) {
                    const float* cp = &lds_in[(icl * CR + 2 * oh_g + rr) * CCP + 4 * owp];
                    float2 a = *(const float2*)&cp[0];
                    float2 b = *(const float2*)&cp[2];
                    patch[rr][0] = a.x; patch[rr][1] = a.y;
                    patch[rr][2] = b.x; patch[rr][3] = b.y;
                    patch[rr][4] = cp[4];
                }
                const float* __restrict__ wk = w3T + (size_t)(ic0 + icl) * 576 + ocg16;
#pragma unroll
                for (int k = 0; k < 9; ++k) {
                    const int kh = k / 3, kw = k - kh * 3;
#pragma unroll
                    for (int e = 0; e < 16; ++e) {
                        const float w = wk[k * 64 + e];
                        acc[0][e] = fmaf(patch[kh][kw], w, acc[0][e]);
                        acc[1][e] = fmaf(patch[kh][2 + kw], w, acc[1][e]);
                    }
                }
            }
        }
    }
    if (lane < 40) {
#pragma unroll
        for (int e = 0; e < 16; ++e) {
            const int oc = ocg16 + e;
            const float bb = bias[oc];
            float2 r0;
            r0.x = fmaxf(acc[0][e] + bb, 0.f);
            r0.y = fmaxf(acc[1][e] + bb, 0.f);
            *(float2*)&out[((size_t)n * 64 + oc) * 160 + oh_g * 10 + 2 * owp] = r0;
        }
    }
}

// ---------- fused conv4 + sensory sums: grid 256 (frame), block 256 ----------
__global__ __launch_bounds__(256) void k_sens4(
    const float* __restrict__ conv3o,  // [256][64][16][10]
    const float* __restrict__ w4,      // [32][64][3][3] raw
    const float* __restrict__ b4,
    const float* __restrict__ relpos,  // [256(frames flattened from B,S)][3] = [32][8][3]
    const float* __restrict__ smu, const float* __restrict__ ssig,
    const float* __restrict__ sw, const float* __restrict__ sev,
    const float* __restrict__ smask,
    const float* __restrict__ iw, const float* __restrict__ ib,
    float* __restrict__ wns, float* __restrict__ wds)  // [256][48]
{
    constexpr int CR = 17, CW = 12;           // rows -1..15, cols -1..10
    constexpr int NS = 1283, U = 48, NG = 5;
    __shared__ float lds_in[64 * CR * CW];    // 51 KB
    __shared__ float lds_inp[NS];             // 5.1 KB
    __shared__ float lds_pn[NG * U], lds_pd[NG * U];

    const int tid = threadIdx.x;
    const int bs = blockIdx.x;
    const float* ibase = conv3o + (size_t)bs * 64 * 160;

    for (int idx = tid; idx < 64 * CR * CW; idx += 256) {
        int ic = idx / (CR * CW);
        int rem = idx - ic * (CR * CW);
        int r = rem / CW, c = rem - r * CW;
        int ih = r - 1, iww = c - 1;
        float v = 0.f;
        if (ih >= 0 && ih < 16 && iww >= 0 && iww < 10)
            v = ibase[ic * 160 + ih * 10 + iww];
        lds_in[idx] = v;
    }
    if (tid < 3) lds_inp[1280 + tid] = relpos[bs * 3 + tid] * iw[1280 + tid] + ib[1280 + tid];
    __syncthreads();

    // conv4: thread -> (oc = tid>>3, pg = tid&7); 5 outputs (ow 0..4), oh = pg
    const int oc = tid >> 3, pg = tid & 7;
    float acc5[5];
#pragma unroll
    for (int j = 0; j < 5; ++j) acc5[j] = 0.f;
    const float* wp = w4 + oc * 576;
    for (int ic = 0; ic < 64; ++ic) {
        float rv[3][12];
#pragma unroll
        for (int rr = 0; rr < 3; ++rr) {
            const float* rp = &lds_in[(ic * CR + 2 * pg + rr) * CW];
            float4 a = *(const float4*)&rp[0];
            float4 b = *(const float4*)&rp[4];
            float4 c = *(const float4*)&rp[8];
            rv[rr][0] = a.x; rv[rr][1] = a.y; rv[rr][2] = a.z; rv[rr][3] = a.w;
            rv[rr][4] = b.x; rv[rr][5] = b.y; rv[rr][6] = b.z; rv[rr][7] = b.w;
            rv[rr][8] = c.x; rv[rr][9] = c.y; rv[rr][10] = c.z; rv[rr][11] = c.w;
        }
        float wv[9];
#pragma unroll
        for (int k = 0; k < 9; ++k) wv[k] = wp[ic * 9 + k];
#pragma unroll
        for (int k = 0; k < 9; ++k) {
            const int kh = k / 3, kw = k - kh * 3;
#pragma unroll
            for (int j = 0; j < 5; ++j)
                acc5[j] = fmaf(rv[kh][2 * j + kw], wv[k], acc5[j]);
        }
    }
    const float bb = b4[oc];
#pragma unroll
    for (int j = 0; j < 5; ++j) {
        const int f = oc * 40 + pg * 5 + j;
        lds_inp[f] = fmaxf(acc5[j] + bb, 0.f) * iw[f] + ib[f];
    }
    __syncthreads();

    // sensory sums
    if (tid < NG * U) {
        const int p = tid / U, j = tid % U;
        const int i0 = (NS * p) / NG, i1 = (NS * (p + 1)) / NG;
        float pn = 0.f, pd = 0.f;
        for (int i = i0; i < i1; ++i) {
            float x = lds_inp[i];
            int o = i * U + j;
            float arg = ssig[o] * (x - smu[o]);
            float e = __expf(-arg);
            float r = 1.f / (1.f + e);
            float sact = sw[o] * r * smask[o];
            pn = fmaf(sact, sev[o], pn);
            pd += sact;
        }
        lds_pn[tid] = pn;
        lds_pd[tid] = pd;
    }
    __syncthreads();
    if (tid < U) {
        float sn = 0.f, sd = 0.f;
#pragma unroll
        for (int p = 0; p < NG; ++p) { sn += lds_pn[p * U + tid]; sd += lds_pd[p * U + tid]; }
        wns[bs * U + tid] = sn;
        wds[bs * U + tid] = sd;
    }
}

// ---------- LTC recurrence + head ----------
__global__ __launch_bounds__(192) void k_recur(
    const float* __restrict__ wns, const float* __restrict__ wds,
    const float* __restrict__ gleak, const float* __restrict__ vleak,
    const float* __restrict__ cm,
    const float* __restrict__ mu, const float* __restrict__ sigma,
    const float* __restrict__ wsyn, const float* __restrict__ erev,
    const float* __restrict__ mask,
    const float* __restrict__ ow_, const float* __restrict__ ob_,
    const float* __restrict__ hw, const float* __restrict__ hb,
    float* __restrict__ outp)
{
    constexpr int U = 48, S = 8, NU = 6, P = 4;
    constexpr float LOG2E = 1.44269504088896f;
    __shared__ float A[U * U], Bc[U * U], WE[U * U], WM[U * U];
    __shared__ float vv[U];
    __shared__ float pn[P * U], pd[P * U];
    __shared__ float out4[4];

    const int tid = threadIdx.x;
    const int b = blockIdx.x;
    const int p = tid / U, j = tid % U;

    for (int idx = tid; idx < U * U; idx += 192) {
        float sg = sigma[idx], m = mu[idx], w = wsyn[idx] * mask[idx];
        A[idx] = -sg * LOG2E;
        Bc[idx] = sg * m * LOG2E;
        WE[idx] = w * erev[idx];
        WM[idx] = w;
    }
    if (tid < U) vv[tid] = 0.f;
    float cmt = 0.f, gl = 0.f, glvl = 0.f;
    if (tid < U) {
        cmt = cm[tid] * 6.f;
        gl = gleak[tid];
        glvl = gl * vleak[tid];
    }
    float acc_o = 0.f;
    __syncthreads();

    for (int s = 0; s < S; ++s) {
        float wn = 0.f, wd = 0.f;
        if (tid < U) {
            wn = wns[(b * S + s) * U + tid];
            wd = wds[(b * S + s) * U + tid];
        }
        for (int u = 0; u < NU; ++u) {
            float an = 0.f, ad = 0.f;
            const int i0 = p * 12;
#pragma unroll
            for (int ii = 0; ii < 12; ++ii) {
                int i = i0 + ii;
                float vi = vv[i];
                int o = i * U + j;
                float e = exp2f(fmaf(vi, A[o], Bc[o]));
                float r = 1.f / (1.f + e);
                an = fmaf(WE[o], r, an);
                ad = fmaf(WM[o], r, ad);
            }
            pn[tid] = an;
            pd[tid] = ad;
            __syncthreads();
            if (tid < U) {
                float num = fmaf(cmt, vv[tid], glvl) + wn;
                float den = cmt + gl + wd;
#pragma unroll
                for (int q = 0; q < P; ++q) { num += pn[q * U + tid]; den += pd[q * U + tid]; }
                vv[tid] = num / (den + 1e-8f);
            }
            __syncthreads();
        }
        if (tid < 4) acc_o += vv[tid];
    }
    if (tid < 4) out4[tid] = (acc_o * 0.125f) * ow_[tid] + ob_[tid];
    __syncthreads();
    if (tid < 2) {
        float r = hb[tid];
#pragma unroll
        for (int k = 0; k < 4; ++k) r += out4[k] * hw[k * 2 + tid];
        outp[b * 2 + tid] = tanhf(r);
    }
}

// ---------------------------------------------------------------------------
extern "C" void kernel_launch(void* const* d_in, const int* in_sizes, int n_in,
                              void* d_out, int out_size, void* d_ws, size_t ws_size,
                              hipStream_t stream) {
    const float* depth  = (const float*)d_in[0];
    const float* relpos = (const float*)d_in[1];
    const float* w1 = (const float*)d_in[2];
    const float* b1 = (const float*)d_in[3];
    const float* w2 = (const float*)d_in[4];
    const float* b2 = (const float*)d_in[5];
    const float* w3 = (const float*)d_in[6];
    const float* b3 = (const float*)d_in[7];
    const float* w4 = (const float*)d_in[8];
    const float* b4 = (const float*)d_in[9];
    const float* gleak = (const float*)d_in[10];
    const float* vleak = (const float*)d_in[11];
    const float* cm    = (const float*)d_in[12];
    const float* mu    = (const float*)d_in[13];
    const float* sigma = (const float*)d_in[14];
    const float* wsyn  = (const float*)d_in[15];
    const float* erev  = (const float*)d_in[16];
    const float* mask  = (const float*)d_in[17];
    const float* smu   = (const float*)d_in[18];
    const float* ssig  = (const float*)d_in[19];
    const float* sw    = (const float*)d_in[20];
    const float* sev   = (const float*)d_in[21];
    const float* smask = (const float*)d_in[22];
    const float* iw    = (const float*)d_in[23];
    const float* ib    = (const float*)d_in[24];
    const float* ow_   = (const float*)d_in[25];
    const float* ob_   = (const float*)d_in[26];
    const float* hw    = (const float*)d_in[27];
    const float* hb    = (const float*)d_in[28];

    float* ws = (float*)d_ws;
    float* conv2o = ws;                     // 10,485,760
    float* conv3o = conv2o + 10485760;      //  2,621,440
    float* w2T    = conv3o + 2621440;       //     73,728
    float* w3T    = w2T + 73728;            //     36,864
    float* wnsb   = w3T + 36864;            //     12,288
    float* wdsb   = wnsb + 12288;           //     12,288

    k_transpose_w<<<dim3((73728 + 255) / 256), dim3(256), 0, stream>>>(w2, w2T, 64, 128);
    k_transpose_w<<<dim3((36864 + 255) / 256), dim3(256), 0, stream>>>(w3, w3T, 64, 64);

    k_conv12<<<dim3(512), dim3(256), 0, stream>>>(depth, w1, b1, w2T, b2, conv2o);
    k_conv3<<<dim3(256), dim3(512), 0, stream>>>(conv2o, w3T, b3, conv3o);
    k_sens4<<<dim3(256), dim3(256), 0, stream>>>(conv3o, w4, b4, relpos,
                                                 smu, ssig, sw, sev, smask,
                                                 iw, ib, wnsb, wdsb);
    k_recur<<<dim3(32), dim3(192), 0, stream>>>(wnsb, wdsb, gleak, vleak, cm, mu, sigma,
                                                wsyn, erev, mask, ow_, ob_, hw, hb,
                                                (float*)d_out);
}

// Round 10
// 581.178 us; speedup vs baseline: 2.5283x; 1.5088x over previous
//
#include <hip/hip_runtime.h>
#include <math.h>

// ---------------------------------------------------------------------------
// Round 10: conv1+conv2 via MFMA (bf16x3 split), everything else from round 8.
//  conv2 = 9 shift-GEMMs over the conv1 LDS tile (no im2col copy):
//   - block = (frame, quarter): out 8oh x 20ow x 64oc; 640 thr = 10 waves
//   - wave  = one 32px x 32oc tile (5 Mt x 2 Nt), mfma_f32_32x32x16_bf16
//   - K loop: 8 icb x 16 ic; per icb: conv1 (VALU, fp32) -> LDS bf16 hi/lo,
//     parity-split layout [icblk][parity][row17][col2 23][ic8] so each
//     A-frag is one conflict-free ds_read_b128 (unit-stride cols).
//   - weights pre-packed B-fragment-ready (k_prep_wB), loaded per icb.
// ---------------------------------------------------------------------------

typedef __attribute__((ext_vector_type(8))) short short8v;
typedef __attribute__((ext_vector_type(16))) float float16v;

__device__ __forceinline__ unsigned short f2bf(float x) {
    unsigned int u = __float_as_uint(x);
    u = u + 0x7fffu + ((u >> 16) & 1u);
    return (unsigned short)(u >> 16);
}
__device__ __forceinline__ float bf2f(unsigned short b) {
    return __uint_as_float(((unsigned int)b) << 16);
}

// ---------- prep: w2 [64][128][3][3] -> B-fragment order, bf16 hi/lo ----------
// idx = ((((Nt*8+icb)*9+s)*2+hl)*64+lane)*8+j
__global__ __launch_bounds__(256) void k_prep_wB(const float* __restrict__ w2,
                                                 unsigned short* __restrict__ wB) {
    int idx = blockIdx.x * 256 + threadIdx.x;
    if (idx >= 294912) return;
    int j = idx & 7;
    int lane = (idx >> 3) & 63;
    int hl = (idx >> 9) & 1;
    int t = idx >> 10;
    int s = t % 9;
    int u = t / 9;
    int icb = u & 7;
    int Nt = u >> 3;
    int oc = Nt * 32 + (lane & 31);
    int ic = icb * 16 + 8 * (lane >> 5) + j;
    int kh = s / 3, kw = s % 3;
    float w = w2[((size_t)oc * 128 + ic) * 9 + kh * 3 + kw];
    unsigned short h = f2bf(w);
    wB[idx] = hl ? f2bf(w - bf2f(h)) : h;
}

__global__ void k_transpose_w(const float* __restrict__ src, float* __restrict__ dst,
                              int OC, int IC) {
    int idx = blockIdx.x * blockDim.x + threadIdx.x;
    int total = OC * IC * 9;
    if (idx >= total) return;
    int oc = idx / (IC * 9);
    int rem = idx % (IC * 9);
    int ic = rem / 9;
    int k = rem % 9;
    dst[(ic * 9 + k) * OC + oc] = src[idx];
}

// ---------- fused conv1+conv2 MFMA: grid 1024 (frame x quarter), block 640 ----------
__global__ __launch_bounds__(640) void k_conv12(
    const float* __restrict__ depth,   // [256][128][80]
    const float* __restrict__ w1g, const float* __restrict__ b1g,
    const unsigned short* __restrict__ wB,
    const float* __restrict__ b2,
    float* __restrict__ out)           // [256][64][32][20]
{
    __shared__ float lds_d[35 * 84];               // 11.76 KB
    __shared__ unsigned short c1h[12512];          // [2][2][17][23][8] = 25.0 KB
    __shared__ unsigned short c1l[12512];          // 25.0 KB

    const int tid = threadIdx.x;
    const int lane = tid & 63;
    const int wv = __builtin_amdgcn_readfirstlane(tid >> 6);   // 0..9
    const int Nt = wv & 1;
    const int Mt = wv >> 1;            // 0..4
    const int n = blockIdx.x >> 2;
    const int q = blockIdx.x & 3;

    // stage depth tile: rows 32q-3..+34, cols -1..80
    const float* dimg = depth + (size_t)n * 128 * 80;
    const int dr0 = 32 * q - 3;
    for (int idx = tid; idx < 35 * 82; idx += 640) {
        int rr = idx / 82, c = idx - rr * 82;
        int gr = dr0 + rr, gc = c - 1;
        float v = 0.f;
        if (gr >= 0 && gr < 128 && gc >= 0 && gc < 80) v = dimg[gr * 80 + gc];
        lds_d[rr * 84 + c] = v;
    }

    float16v acc = {0.f, 0.f, 0.f, 0.f, 0.f, 0.f, 0.f, 0.f,
                    0.f, 0.f, 0.f, 0.f, 0.f, 0.f, 0.f, 0.f};

    const int l31 = lane & 31;
    const int px = Mt * 32 + l31;      // 0..159 within quarter
    const int oh = px / 20;            // 0..7
    const int ow = px - oh * 20;       // 0..19
    const int icblk = lane >> 5;
    const int baseA = icblk * 782 + oh * 46 + ow;   // elem/8 units

    for (int icb = 0; icb < 8; ++icb) {
        // B-fragment loads (global, coalesced; overlap conv1 compute)
        short8v Bh[9], Bl[9];
        const unsigned short* wchunk = wB + (size_t)(Nt * 8 + icb) * 9216 + lane * 8;
#pragma unroll
        for (int s = 0; s < 9; ++s) {
            Bh[s] = *(const short8v*)(wchunk + s * 1024);
            Bl[s] = *(const short8v*)(wchunk + s * 1024 + 512);
        }

        __syncthreads();   // prev MFMA reads done before c1 overwrite
        // conv1 phase: items (r 0..16, C 0..41), 16 ics each, fp32 -> bf16 hi/lo
        for (int it = tid; it < 714; it += 640) {
            const int r = it / 42, C = it - r * 42;
            const int g = 16 * q - 1 + r;     // conv1 global row
            const int cc = C - 1;             // conv1 global col
            const int p = C & 1, cc2 = C >> 1;
            const bool valid = (g >= 0 && g < 64 && cc >= 0 && cc < 40);
            float d[3][3];
            if (valid) {
                const float* dp = &lds_d[(2 * r) * 84 + (2 * C - 2)];
#pragma unroll
                for (int kh2 = 0; kh2 < 3; ++kh2) {
                    float2 a = *(const float2*)&dp[kh2 * 84];
                    d[kh2][0] = a.x; d[kh2][1] = a.y; d[kh2][2] = dp[kh2 * 84 + 2];
                }
            }
#pragma unroll
            for (int icl = 0; icl < 16; icl += 2) {
                unsigned int hpack = 0, lpack = 0;
#pragma unroll
                for (int tt = 0; tt < 2; ++tt) {
                    float v = 0.f;
                    if (valid) {
                        const int ic = icb * 16 + icl + tt;
                        float sacc = b1g[ic];
#pragma unroll
                        for (int kh2 = 0; kh2 < 3; ++kh2)
#pragma unroll
                            for (int kw2 = 0; kw2 < 3; ++kw2)
                                sacc = fmaf(d[kh2][kw2], w1g[ic * 9 + kh2 * 3 + kw2], sacc);
                        v = fmaxf(sacc, 0.f);
                    }
                    unsigned short h = f2bf(v);
                    unsigned short l = f2bf(v - bf2f(h));
                    hpack |= ((unsigned int)h) << (16 * tt);
                    lpack |= ((unsigned int)l) << (16 * tt);
                }
                const int off = ((((icl >> 3) * 2 + p) * 17 + r) * 23 + cc2) * 8 + (icl & 7);
                *(unsigned int*)&c1h[off] = hpack;
                *(unsigned int*)&c1l[off] = lpack;
            }
        }
        __syncthreads();

        // MFMA phase: 9 shift-GEMM slices x 3 split products
#pragma unroll
        for (int s = 0; s < 9; ++s) {
            const int kh = s / 3, kw = s % 3;
            const int offe = (baseA + (kw & 1) * 391 + kh * 23 + (kw >> 1)) * 8;
            short8v Ah = *(const short8v*)&c1h[offe];
            short8v Al = *(const short8v*)&c1l[offe];
            acc = __builtin_amdgcn_mfma_f32_32x32x16_bf16(Ah, Bh[s], acc, 0, 0, 0);
            acc = __builtin_amdgcn_mfma_f32_32x32x16_bf16(Ah, Bl[s], acc, 0, 0, 0);
            acc = __builtin_amdgcn_mfma_f32_32x32x16_bf16(Al, Bh[s], acc, 0, 0, 0);
        }
    }

    // epilogue: D row = (reg&3)+8*(reg>>2)+4*(lane>>5), col = lane&31
    const int oc = Nt * 32 + l31;
    const float bb = b2[oc];
    float* obase = out + ((size_t)n * 64 + oc) * 640;
#pragma unroll
    for (int qd = 0; qd < 4; ++qd) {
        const int px4 = q * 160 + Mt * 32 + 8 * qd + 4 * icblk;
        float4 v;
        v.x = fmaxf(acc[4 * qd + 0] + bb, 0.f);
        v.y = fmaxf(acc[4 * qd + 1] + bb, 0.f);
        v.z = fmaxf(acc[4 * qd + 2] + bb, 0.f);
        v.w = fmaxf(acc[4 * qd + 3] + bb, 0.f);
        *(float4*)&obase[px4] = v;
    }
}

// ---------- conv3: grid 256 (frame), block 512 (unchanged, round 8) ----------
__global__ __launch_bounds__(512, 2) void k_conv3(
    const float* __restrict__ in,    // [256][64][32][20]
    const float* __restrict__ w3T,   // [64][9][64]
    const float* __restrict__ bias,
    float* __restrict__ out)         // [256][64][16][10]
{
    constexpr int IC = 64, IH = 32, IW = 20;
    constexpr int CR = 33, CC = 22, CCP = 26, ICB = 8;
    __shared__ float lds_in[ICB * CR * CCP];

    const int tid = threadIdx.x;
    const int lane = tid & 63;
    const int wv = tid >> 6;
    const int ocg16 = __builtin_amdgcn_readfirstlane(wv >> 1) * 16;
    const int half = __builtin_amdgcn_readfirstlane(wv & 1);
    const int n = blockIdx.x;
    const float* ibase = in + (size_t)n * IC * IH * IW;

    float acc[2][16];
#pragma unroll
    for (int p = 0; p < 2; ++p)
#pragma unroll
        for (int e = 0; e < 16; ++e) acc[p][e] = 0.f;

    const int oh_l = lane / 5, owp = lane - oh_l * 5;
    const int oh_g = half * 8 + oh_l;

    for (int icb = 0; icb < IC / ICB; ++icb) {
        const int ic0 = icb * ICB;
        __syncthreads();
        for (int idx = tid; idx < ICB * CR * CC; idx += 512) {
            int icl = idx / (CR * CC);
            int rem = idx - icl * (CR * CC);
            int r = rem / CC, c = rem - r * CC;
            int ih = r - 1, iw = c - 1;
            float v = 0.f;
            if (ih >= 0 && ih < IH && iw >= 0 && iw < IW)
                v = ibase[((size_t)(ic0 + icl) * IH + ih) * IW + iw];
            lds_in[(icl * CR + r) * CCP + c] = v;
        }
        __syncthreads();
        if (lane < 40) {
#pragma unroll
            for (int icl = 0; icl < ICB; ++icl) {
                float patch[3][5];
#pragma unroll
                for (int rr = 0; rr < 3; ++rr) {
                    const float* cp = &lds_in[(icl * CR + 2 * oh_g + rr) * CCP + 4 * owp];
                    float2 a = *(const float2*)&cp[0];
                    float2 b = *(const float2*)&cp[2];
                    patch[rr][0] = a.x; patch[rr][1] = a.y;
                    patch[rr][2] = b.x; patch[rr][3] = b.y;
                    patch[rr][4] = cp[4];
                }
                const float* __restrict__ wk = w3T + (size_t)(ic0 + icl) * 576 + ocg16;
#pragma unroll
                for (int k = 0; k < 9; ++k) {
                    const int kh = k / 3, kw = k - kh * 3;
#pragma unroll
                    for (int e = 0; e < 16; ++e) {
                        const float w = wk[k * 64 + e];
                        acc[0][e] = fmaf(patch[kh][kw], w, acc[0][e]);
                        acc[1][e] = fmaf(patch[kh][2 + kw], w, acc[1][e]);
                    }
                }
            }
        }
    }
    if (lane < 40) {
#pragma unroll
        for (int e = 0; e < 16; ++e) {
            const int oc = ocg16 + e;
            const float bb = bias[oc];
            float2 r0;
            r0.x = fmaxf(acc[0][e] + bb, 0.f);
            r0.y = fmaxf(acc[1][e] + bb, 0.f);
            *(float2*)&out[((size_t)n * 64 + oc) * 160 + oh_g * 10 + 2 * owp] = r0;
        }
    }
}

// ---------- fused conv4 + sensory sums (unchanged, round 8) ----------
__global__ __launch_bounds__(256) void k_sens4(
    const float* __restrict__ conv3o,
    const float* __restrict__ w4, const float* __restrict__ b4,
    const float* __restrict__ relpos,
    const float* __restrict__ smu, const float* __restrict__ ssig,
    const float* __restrict__ sw, const float* __restrict__ sev,
    const float* __restrict__ smask,
    const float* __restrict__ iw, const float* __restrict__ ib,
    float* __restrict__ wns, float* __restrict__ wds)
{
    constexpr int CR = 17, CW = 12;
    constexpr int NS = 1283, U = 48, NG = 5;
    __shared__ float lds_in[64 * CR * CW];
    __shared__ float lds_inp[NS];
    __shared__ float lds_pn[NG * U], lds_pd[NG * U];

    const int tid = threadIdx.x;
    const int bs = blockIdx.x;
    const float* ibase = conv3o + (size_t)bs * 64 * 160;

    for (int idx = tid; idx < 64 * CR * CW; idx += 256) {
        int ic = idx / (CR * CW);
        int rem = idx - ic * (CR * CW);
        int r = rem / CW, c = rem - r * CW;
        int ih = r - 1, iww = c - 1;
        float v = 0.f;
        if (ih >= 0 && ih < 16 && iww >= 0 && iww < 10)
            v = ibase[ic * 160 + ih * 10 + iww];
        lds_in[idx] = v;
    }
    if (tid < 3) lds_inp[1280 + tid] = relpos[bs * 3 + tid] * iw[1280 + tid] + ib[1280 + tid];
    __syncthreads();

    const int oc = tid >> 3, pg = tid & 7;
    float acc5[5];
#pragma unroll
    for (int j = 0; j < 5; ++j) acc5[j] = 0.f;
    const float* wp = w4 + oc * 576;
    for (int ic = 0; ic < 64; ++ic) {
        float rv[3][12];
#pragma unroll
        for (int rr = 0; rr < 3; ++rr) {
            const float* rp = &lds_in[(ic * CR + 2 * pg + rr) * CW];
            float4 a = *(const float4*)&rp[0];
            float4 b = *(const float4*)&rp[4];
            float4 c = *(const float4*)&rp[8];
            rv[rr][0] = a.x; rv[rr][1] = a.y; rv[rr][2] = a.z; rv[rr][3] = a.w;
            rv[rr][4] = b.x; rv[rr][5] = b.y; rv[rr][6] = b.z; rv[rr][7] = b.w;
            rv[rr][8] = c.x; rv[rr][9] = c.y; rv[rr][10] = c.z; rv[rr][11] = c.w;
        }
        float wv[9];
#pragma unroll
        for (int k = 0; k < 9; ++k) wv[k] = wp[ic * 9 + k];
#pragma unroll
        for (int k = 0; k < 9; ++k) {
            const int kh = k / 3, kw = k - kh * 3;
#pragma unroll
            for (int j = 0; j < 5; ++j)
                acc5[j] = fmaf(rv[kh][2 * j + kw], wv[k], acc5[j]);
        }
    }
    const float bb = b4[oc];
#pragma unroll
    for (int j = 0; j < 5; ++j) {
        const int f = oc * 40 + pg * 5 + j;
        lds_inp[f] = fmaxf(acc5[j] + bb, 0.f) * iw[f] + ib[f];
    }
    __syncthreads();

    if (tid < NG * U) {
        const int p = tid / U, j = tid % U;
        const int i0 = (NS * p) / NG, i1 = (NS * (p + 1)) / NG;
        float pn = 0.f, pd = 0.f;
        for (int i = i0; i < i1; ++i) {
            float x = lds_inp[i];
            int o = i * U + j;
            float arg = ssig[o] * (x - smu[o]);
            float e = __expf(-arg);
            float r = 1.f / (1.f + e);
            float sact = sw[o] * r * smask[o];
            pn = fmaf(sact, sev[o], pn);
            pd += sact;
        }
        lds_pn[tid] = pn;
        lds_pd[tid] = pd;
    }
    __syncthreads();
    if (tid < U) {
        float sn = 0.f, sd = 0.f;
#pragma unroll
        for (int p = 0; p < NG; ++p) { sn += lds_pn[p * U + tid]; sd += lds_pd[p * U + tid]; }
        wns[bs * U + tid] = sn;
        wds[bs * U + tid] = sd;
    }
}

// ---------- LTC recurrence + head (unchanged) ----------
__global__ __launch_bounds__(192) void k_recur(
    const float* __restrict__ wns, const float* __restrict__ wds,
    const float* __restrict__ gleak, const float* __restrict__ vleak,
    const float* __restrict__ cm,
    const float* __restrict__ mu, const float* __restrict__ sigma,
    const float* __restrict__ wsyn, const float* __restrict__ erev,
    const float* __restrict__ mask,
    const float* __restrict__ ow_, const float* __restrict__ ob_,
    const float* __restrict__ hw, const float* __restrict__ hb,
    float* __restrict__ outp)
{
    constexpr int U = 48, S = 8, NU = 6, P = 4;
    constexpr float LOG2E = 1.44269504088896f;
    __shared__ float A[U * U], Bc[U * U], WE[U * U], WM[U * U];
    __shared__ float vv[U];
    __shared__ float pn[P * U], pd[P * U];
    __shared__ float out4[4];

    const int tid = threadIdx.x;
    const int b = blockIdx.x;
    const int p = tid / U, j = tid % U;

    for (int idx = tid; idx < U * U; idx += 192) {
        float sg = sigma[idx], m = mu[idx], w = wsyn[idx] * mask[idx];
        A[idx] = -sg * LOG2E;
        Bc[idx] = sg * m * LOG2E;
        WE[idx] = w * erev[idx];
        WM[idx] = w;
    }
    if (tid < U) vv[tid] = 0.f;
    float cmt = 0.f, gl = 0.f, glvl = 0.f;
    if (tid < U) {
        cmt = cm[tid] * 6.f;
        gl = gleak[tid];
        glvl = gl * vleak[tid];
    }
    float acc_o = 0.f;
    __syncthreads();

    for (int s = 0; s < S; ++s) {
        float wn = 0.f, wd = 0.f;
        if (tid < U) {
            wn = wns[(b * S + s) * U + tid];
            wd = wds[(b * S + s) * U + tid];
        }
        for (int u = 0; u < NU; ++u) {
            float an = 0.f, ad = 0.f;
            const int i0 = p * 12;
#pragma unroll
            for (int ii = 0; ii < 12; ++ii) {
                int i = i0 + ii;
                float vi = vv[i];
                int o = i * U + j;
                float e = exp2f(fmaf(vi, A[o], Bc[o]));
                float r = 1.f / (1.f + e);
                an = fmaf(WE[o], r, an);
                ad = fmaf(WM[o], r, ad);
            }
            pn[tid] = an;
            pd[tid] = ad;
            __syncthreads();
            if (tid < U) {
                float num = fmaf(cmt, vv[tid], glvl) + wn;
                float den = cmt + gl + wd;
#pragma unroll
                for (int qq = 0; qq < P; ++qq) { num += pn[qq * U + tid]; den += pd[qq * U + tid]; }
                vv[tid] = num / (den + 1e-8f);
            }
            __syncthreads();
        }
        if (tid < 4) acc_o += vv[tid];
    }
    if (tid < 4) out4[tid] = (acc_o * 0.125f) * ow_[tid] + ob_[tid];
    __syncthreads();
    if (tid < 2) {
        float r = hb[tid];
#pragma unroll
        for (int k = 0; k < 4; ++k) r += out4[k] * hw[k * 2 + tid];
        outp[b * 2 + tid] = tanhf(r);
    }
}

// ---------------------------------------------------------------------------
extern "C" void kernel_launch(void* const* d_in, const int* in_sizes, int n_in,
                              void* d_out, int out_size, void* d_ws, size_t ws_size,
                              hipStream_t stream) {
    const float* depth  = (const float*)d_in[0];
    const float* relpos = (const float*)d_in[1];
    const float* w1 = (const float*)d_in[2];
    const float* b1 = (const float*)d_in[3];
    const float* w2 = (const float*)d_in[4];
    const float* b2 = (const float*)d_in[5];
    const float* w3 = (const float*)d_in[6];
    const float* b3 = (const float*)d_in[7];
    const float* w4 = (const float*)d_in[8];
    const float* b4 = (const float*)d_in[9];
    const float* gleak = (const float*)d_in[10];
    const float* vleak = (const float*)d_in[11];
    const float* cm    = (const float*)d_in[12];
    const float* mu    = (const float*)d_in[13];
    const float* sigma = (const float*)d_in[14];
    const float* wsyn  = (const float*)d_in[15];
    const float* erev  = (const float*)d_in[16];
    const float* mask  = (const float*)d_in[17];
    const float* smu   = (const float*)d_in[18];
    const float* ssig  = (const float*)d_in[19];
    const float* sw    = (const float*)d_in[20];
    const float* sev   = (const float*)d_in[21];
    const float* smask = (const float*)d_in[22];
    const float* iw    = (const float*)d_in[23];
    const float* ib    = (const float*)d_in[24];
    const float* ow_   = (const float*)d_in[25];
    const float* ob_   = (const float*)d_in[26];
    const float* hw    = (const float*)d_in[27];
    const float* hb    = (const float*)d_in[28];

    float* ws = (float*)d_ws;
    float* conv2o = ws;                       // 10,485,760
    float* conv3o = conv2o + 10485760;        //  2,621,440
    float* w3T    = conv3o + 2621440;         //     36,864
    float* wBf    = w3T + 36864;              //    147,456 floats = 294,912 bf16
    float* wnsb   = wBf + 147456;             //     12,288
    float* wdsb   = wnsb + 12288;             //     12,288
    unsigned short* wB = (unsigned short*)wBf;

    k_prep_wB<<<dim3(1152), dim3(256), 0, stream>>>(w2, wB);
    k_transpose_w<<<dim3((36864 + 255) / 256), dim3(256), 0, stream>>>(w3, w3T, 64, 64);

    k_conv12<<<dim3(1024), dim3(640), 0, stream>>>(depth, w1, b1, wB, b2, conv2o);
    k_conv3<<<dim3(256), dim3(512), 0, stream>>>(conv2o, w3T, b3, conv3o);
    k_sens4<<<dim3(256), dim3(256), 0, stream>>>(conv3o, w4, b4, relpos,
                                                 smu, ssig, sw, sev, smask,
                                                 iw, ib, wnsb, wdsb);
    k_recur<<<dim3(32), dim3(192), 0, stream>>>(wnsb, wdsb, gleak, vleak, cm, mu, sigma,
                                                wsyn, erev, mask, ow_, ob_, hw, hb,
                                                (float*)d_out);
}

// Round 11
// 515.440 us; speedup vs baseline: 2.8507x; 1.1275x over previous
//
#include <hip/hip_runtime.h>
#include <math.h>

// ---------------------------------------------------------------------------
// Round 11:
//  - conv12 (MFMA, unchanged core) now writes conv2 output as bf16 hi/lo in
//    NHWC [n][px640][ic64] (fp32 NCHW intermediate deleted).
//  - conv3 rewritten as LDS-free MFMA: A-fragments are predicated 16B global
//    loads straight from the NHWC bf16 arrays (L1/L2-resident), B pre-packed.
//    No barriers, 10 waves/block, 108 MFMA/wave (bf16x3 split).
//  - sens4 / recur unchanged (round 8).
// ---------------------------------------------------------------------------

typedef __attribute__((ext_vector_type(8))) short short8v;
typedef __attribute__((ext_vector_type(16))) float float16v;

__device__ __forceinline__ unsigned short f2bf(float x) {
    unsigned int u = __float_as_uint(x);
    u = u + 0x7fffu + ((u >> 16) & 1u);
    return (unsigned short)(u >> 16);
}
__device__ __forceinline__ float bf2f(unsigned short b) {
    return __uint_as_float(((unsigned int)b) << 16);
}

// ---------- prep: conv weights [OC][IC][3][3] -> B-fragment order, bf16 hi/lo ----------
// idx = ((((Nt*NICB+icb)*9+s)*2+hl)*64+lane)*8+j
__global__ __launch_bounds__(256) void k_prep_w(const float* __restrict__ src,
                                                unsigned short* __restrict__ dst,
                                                int NICB, int IC, int total) {
    int idx = blockIdx.x * 256 + threadIdx.x;
    if (idx >= total) return;
    int j = idx & 7;
    int lane = (idx >> 3) & 63;
    int hl = (idx >> 9) & 1;
    int t = idx >> 10;
    int s = t % 9;
    int u = t / 9;
    int icb = u % NICB;
    int Nt = u / NICB;
    int oc = Nt * 32 + (lane & 31);
    int ic = icb * 16 + 8 * (lane >> 5) + j;
    int kh = s / 3, kw = s % 3;
    float w = src[((size_t)oc * IC + ic) * 9 + kh * 3 + kw];
    unsigned short h = f2bf(w);
    dst[idx] = hl ? f2bf(w - bf2f(h)) : h;
}

// ---------- fused conv1+conv2 MFMA: grid 1024 (frame x quarter), block 640 ----------
__global__ __launch_bounds__(640) void k_conv12(
    const float* __restrict__ depth,   // [256][128][80]
    const float* __restrict__ w1g, const float* __restrict__ b1g,
    const unsigned short* __restrict__ wB,
    const float* __restrict__ b2,
    unsigned short* __restrict__ c2h,  // [256][640][64] bf16 hi
    unsigned short* __restrict__ c2l)  // [256][640][64] bf16 lo
{
    __shared__ float lds_d[35 * 84];               // 11.76 KB
    __shared__ unsigned short c1h[12512];          // [2][2][17][23][8] = 25.0 KB
    __shared__ unsigned short c1l[12512];          // 25.0 KB

    const int tid = threadIdx.x;
    const int lane = tid & 63;
    const int wv = __builtin_amdgcn_readfirstlane(tid >> 6);   // 0..9
    const int Nt = wv & 1;
    const int Mt = wv >> 1;            // 0..4
    const int n = blockIdx.x >> 2;
    const int q = blockIdx.x & 3;

    // stage depth tile: rows 32q-3..+34, cols -1..80
    const float* dimg = depth + (size_t)n * 128 * 80;
    const int dr0 = 32 * q - 3;
    for (int idx = tid; idx < 35 * 82; idx += 640) {
        int rr = idx / 82, c = idx - rr * 82;
        int gr = dr0 + rr, gc = c - 1;
        float v = 0.f;
        if (gr >= 0 && gr < 128 && gc >= 0 && gc < 80) v = dimg[gr * 80 + gc];
        lds_d[rr * 84 + c] = v;
    }

    float16v acc = {0.f, 0.f, 0.f, 0.f, 0.f, 0.f, 0.f, 0.f,
                    0.f, 0.f, 0.f, 0.f, 0.f, 0.f, 0.f, 0.f};

    const int l31 = lane & 31;
    const int px = Mt * 32 + l31;      // 0..159 within quarter
    const int oh = px / 20;            // 0..7
    const int ow = px - oh * 20;       // 0..19
    const int icblk = lane >> 5;
    const int baseA = icblk * 782 + oh * 46 + ow;   // elem/8 units

    for (int icb = 0; icb < 8; ++icb) {
        // B-fragment loads (global, coalesced; overlap conv1 compute)
        short8v Bh[9], Bl[9];
        const unsigned short* wchunk = wB + (size_t)(Nt * 8 + icb) * 9216 + lane * 8;
#pragma unroll
        for (int s = 0; s < 9; ++s) {
            Bh[s] = *(const short8v*)(wchunk + s * 1024);
            Bl[s] = *(const short8v*)(wchunk + s * 1024 + 512);
        }

        __syncthreads();   // prev MFMA reads done before c1 overwrite
        // conv1 phase: items (r 0..16, C 0..41), 16 ics each, fp32 -> bf16 hi/lo
        for (int it = tid; it < 714; it += 640) {
            const int r = it / 42, C = it - r * 42;
            const int g = 16 * q - 1 + r;     // conv1 global row
            const int cc = C - 1;             // conv1 global col
            const int p = C & 1, cc2 = C >> 1;
            const bool valid = (g >= 0 && g < 64 && cc >= 0 && cc < 40);
            float d[3][3];
            if (valid) {
                const float* dp = &lds_d[(2 * r) * 84 + (2 * C - 2)];
#pragma unroll
                for (int kh2 = 0; kh2 < 3; ++kh2) {
                    float2 a = *(const float2*)&dp[kh2 * 84];
                    d[kh2][0] = a.x; d[kh2][1] = a.y; d[kh2][2] = dp[kh2 * 84 + 2];
                }
            }
#pragma unroll
            for (int icl = 0; icl < 16; icl += 2) {
                unsigned int hpack = 0, lpack = 0;
#pragma unroll
                for (int tt = 0; tt < 2; ++tt) {
                    float v = 0.f;
                    if (valid) {
                        const int ic = icb * 16 + icl + tt;
                        float sacc = b1g[ic];
#pragma unroll
                        for (int kh2 = 0; kh2 < 3; ++kh2)
#pragma unroll
                            for (int kw2 = 0; kw2 < 3; ++kw2)
                                sacc = fmaf(d[kh2][kw2], w1g[ic * 9 + kh2 * 3 + kw2], sacc);
                        v = fmaxf(sacc, 0.f);
                    }
                    unsigned short h = f2bf(v);
                    unsigned short l = f2bf(v - bf2f(h));
                    hpack |= ((unsigned int)h) << (16 * tt);
                    lpack |= ((unsigned int)l) << (16 * tt);
                }
                const int off = ((((icl >> 3) * 2 + p) * 17 + r) * 23 + cc2) * 8 + (icl & 7);
                *(unsigned int*)&c1h[off] = hpack;
                *(unsigned int*)&c1l[off] = lpack;
            }
        }
        __syncthreads();

        // MFMA phase: 9 shift-GEMM slices x 3 split products
#pragma unroll
        for (int s = 0; s < 9; ++s) {
            const int kh = s / 3, kw = s % 3;
            const int offe = (baseA + (kw & 1) * 391 + kh * 23 + (kw >> 1)) * 8;
            short8v Ah = *(const short8v*)&c1h[offe];
            short8v Al = *(const short8v*)&c1l[offe];
            acc = __builtin_amdgcn_mfma_f32_32x32x16_bf16(Ah, Bh[s], acc, 0, 0, 0);
            acc = __builtin_amdgcn_mfma_f32_32x32x16_bf16(Ah, Bl[s], acc, 0, 0, 0);
            acc = __builtin_amdgcn_mfma_f32_32x32x16_bf16(Al, Bh[s], acc, 0, 0, 0);
        }
    }

    // epilogue: relu(acc+b2) -> bf16 hi/lo NHWC
    const int oc = Nt * 32 + l31;
    const float bb = b2[oc];
#pragma unroll
    for (int qd = 0; qd < 4; ++qd) {
#pragma unroll
        for (int t = 0; t < 4; ++t) {
            const int pxg = q * 160 + Mt * 32 + 8 * qd + 4 * icblk + t;  // 0..639
            float v = fmaxf(acc[4 * qd + t] + bb, 0.f);
            unsigned short h = f2bf(v);
            unsigned short l = f2bf(v - bf2f(h));
            const size_t off = ((size_t)n * 640 + pxg) * 64 + oc;
            c2h[off] = h;
            c2l[off] = l;
        }
    }
}

// ---------- conv3 MFMA, LDS-free: grid 256 (frame), block 640 ----------
__global__ __launch_bounds__(640) void k_conv3(
    const unsigned short* __restrict__ c2h,  // [256][640][64]
    const unsigned short* __restrict__ c2l,
    const unsigned short* __restrict__ wB3,
    const float* __restrict__ bias,
    float* __restrict__ out)                 // [256][64][16][10] fp32 NCHW
{
    const int tid = threadIdx.x;
    const int lane = tid & 63;
    const int wv = __builtin_amdgcn_readfirstlane(tid >> 6);   // 0..9
    const int Nt = wv & 1;
    const int Mt = wv >> 1;                  // 0..4
    const int n = blockIdx.x;
    const int l31 = lane & 31;
    const int icblk = lane >> 5;
    const int px = Mt * 32 + l31;            // 0..159
    const int oh = px / 10, ow = px - oh * 10;

    float16v acc = {0.f, 0.f, 0.f, 0.f, 0.f, 0.f, 0.f, 0.f,
                    0.f, 0.f, 0.f, 0.f, 0.f, 0.f, 0.f, 0.f};
    const size_t fbase = (size_t)n * 640 * 64;

    for (int icb = 0; icb < 4; ++icb) {
        short8v Bh[9], Bl[9];
        const unsigned short* wchunk = wB3 + (size_t)(Nt * 4 + icb) * 9216 + lane * 8;
#pragma unroll
        for (int s = 0; s < 9; ++s) {
            Bh[s] = *(const short8v*)(wchunk + s * 1024);
            Bl[s] = *(const short8v*)(wchunk + s * 1024 + 512);
        }
        const int icoff = icb * 16 + icblk * 8;
#pragma unroll
        for (int s = 0; s < 9; ++s) {
            const int kh = s / 3, kw = s % 3;
            const int row = 2 * oh - 1 + kh;
            const int col = 2 * ow - 1 + kw;
            const bool valid = ((unsigned)row < 32u) && ((unsigned)col < 20u);
            short8v Ah = {0, 0, 0, 0, 0, 0, 0, 0};
            short8v Al = {0, 0, 0, 0, 0, 0, 0, 0};
            if (valid) {
                const size_t off = fbase + ((size_t)(row * 20 + col)) * 64 + icoff;
                Ah = *(const short8v*)(c2h + off);
                Al = *(const short8v*)(c2l + off);
            }
            acc = __builtin_amdgcn_mfma_f32_32x32x16_bf16(Ah, Bh[s], acc, 0, 0, 0);
            acc = __builtin_amdgcn_mfma_f32_32x32x16_bf16(Ah, Bl[s], acc, 0, 0, 0);
            acc = __builtin_amdgcn_mfma_f32_32x32x16_bf16(Al, Bh[s], acc, 0, 0, 0);
        }
    }

    // epilogue: D row=(reg&3)+8*(reg>>2)+4*icblk, col=l31; relu(acc+bias)
    const int oc = Nt * 32 + l31;
    const float bb = bias[oc];
    float* obase = out + ((size_t)n * 64 + oc) * 160;
#pragma unroll
    for (int qd = 0; qd < 4; ++qd) {
        const int px4 = Mt * 32 + 8 * qd + 4 * icblk;
        float4 v;
        v.x = fmaxf(acc[4 * qd + 0] + bb, 0.f);
        v.y = fmaxf(acc[4 * qd + 1] + bb, 0.f);
        v.z = fmaxf(acc[4 * qd + 2] + bb, 0.f);
        v.w = fmaxf(acc[4 * qd + 3] + bb, 0.f);
        *(float4*)&obase[px4] = v;
    }
}

// ---------- fused conv4 + sensory sums (unchanged, round 8) ----------
__global__ __launch_bounds__(256) void k_sens4(
    const float* __restrict__ conv3o,
    const float* __restrict__ w4, const float* __restrict__ b4,
    const float* __restrict__ relpos,
    const float* __restrict__ smu, const float* __restrict__ ssig,
    const float* __restrict__ sw, const float* __restrict__ sev,
    const float* __restrict__ smask,
    const float* __restrict__ iw, const float* __restrict__ ib,
    float* __restrict__ wns, float* __restrict__ wds)
{
    constexpr int CR = 17, CW = 12;
    constexpr int NS = 1283, U = 48, NG = 5;
    __shared__ float lds_in[64 * CR * CW];
    __shared__ float lds_inp[NS];
    __shared__ float lds_pn[NG * U], lds_pd[NG * U];

    const int tid = threadIdx.x;
    const int bs = blockIdx.x;
    const float* ibase = conv3o + (size_t)bs * 64 * 160;

    for (int idx = tid; idx < 64 * CR * CW; idx += 256) {
        int ic = idx / (CR * CW);
        int rem = idx - ic * (CR * CW);
        int r = rem / CW, c = rem - r * CW;
        int ih = r - 1, iww = c - 1;
        float v = 0.f;
        if (ih >= 0 && ih < 16 && iww >= 0 && iww < 10)
            v = ibase[ic * 160 + ih * 10 + iww];
        lds_in[idx] = v;
    }
    if (tid < 3) lds_inp[1280 + tid] = relpos[bs * 3 + tid] * iw[1280 + tid] + ib[1280 + tid];
    __syncthreads();

    const int oc = tid >> 3, pg = tid & 7;
    float acc5[5];
#pragma unroll
    for (int j = 0; j < 5; ++j) acc5[j] = 0.f;
    const float* wp = w4 + oc * 576;
    for (int ic = 0; ic < 64; ++ic) {
        float rv[3][12];
#pragma unroll
        for (int rr = 0; rr < 3; ++rr) {
            const float* rp = &lds_in[(ic * CR + 2 * pg + rr) * CW];
            float4 a = *(const float4*)&rp[0];
            float4 b = *(const float4*)&rp[4];
            float4 c = *(const float4*)&rp[8];
            rv[rr][0] = a.x; rv[rr][1] = a.y; rv[rr][2] = a.z; rv[rr][3] = a.w;
            rv[rr][4] = b.x; rv[rr][5] = b.y; rv[rr][6] = b.z; rv[rr][7] = b.w;
            rv[rr][8] = c.x; rv[rr][9] = c.y; rv[rr][10] = c.z; rv[rr][11] = c.w;
        }
        float wv[9];
#pragma unroll
        for (int k = 0; k < 9; ++k) wv[k] = wp[ic * 9 + k];
#pragma unroll
        for (int k = 0; k < 9; ++k) {
            const int kh = k / 3, kw = k - kh * 3;
#pragma unroll
            for (int j = 0; j < 5; ++j)
                acc5[j] = fmaf(rv[kh][2 * j + kw], wv[k], acc5[j]);
        }
    }
    const float bb = b4[oc];
#pragma unroll
    for (int j = 0; j < 5; ++j) {
        const int f = oc * 40 + pg * 5 + j;
        lds_inp[f] = fmaxf(acc5[j] + bb, 0.f) * iw[f] + ib[f];
    }
    __syncthreads();

    if (tid < NG * U) {
        const int p = tid / U, j = tid % U;
        const int i0 = (NS * p) / NG, i1 = (NS * (p + 1)) / NG;
        float pn = 0.f, pd = 0.f;
        for (int i = i0; i < i1; ++i) {
            float x = lds_inp[i];
            int o = i * U + j;
            float arg = ssig[o] * (x - smu[o]);
            float e = __expf(-arg);
            float r = 1.f / (1.f + e);
            float sact = sw[o] * r * smask[o];
            pn = fmaf(sact, sev[o], pn);
            pd += sact;
        }
        lds_pn[tid] = pn;
        lds_pd[tid] = pd;
    }
    __syncthreads();
    if (tid < U) {
        float sn = 0.f, sd = 0.f;
#pragma unroll
        for (int p = 0; p < NG; ++p) { sn += lds_pn[p * U + tid]; sd += lds_pd[p * U + tid]; }
        wns[bs * U + tid] = sn;
        wds[bs * U + tid] = sd;
    }
}

// ---------- LTC recurrence + head (unchanged) ----------
__global__ __launch_bounds__(192) void k_recur(
    const float* __restrict__ wns, const float* __restrict__ wds,
    const float* __restrict__ gleak, const float* __restrict__ vleak,
    const float* __restrict__ cm,
    const float* __restrict__ mu, const float* __restrict__ sigma,
    const float* __restrict__ wsyn, const float* __restrict__ erev,
    const float* __restrict__ mask,
    const float* __restrict__ ow_, const float* __restrict__ ob_,
    const float* __restrict__ hw, const float* __restrict__ hb,
    float* __restrict__ outp)
{
    constexpr int U = 48, S = 8, NU = 6, P = 4;
    constexpr float LOG2E = 1.44269504088896f;
    __shared__ float A[U * U], Bc[U * U], WE[U * U], WM[U * U];
    __shared__ float vv[U];
    __shared__ float pn[P * U], pd[P * U];
    __shared__ float out4[4];

    const int tid = threadIdx.x;
    const int b = blockIdx.x;
    const int p = tid / U, j = tid % U;

    for (int idx = tid; idx < U * U; idx += 192) {
        float sg = sigma[idx], m = mu[idx], w = wsyn[idx] * mask[idx];
        A[idx] = -sg * LOG2E;
        Bc[idx] = sg * m * LOG2E;
        WE[idx] = w * erev[idx];
        WM[idx] = w;
    }
    if (tid < U) vv[tid] = 0.f;
    float cmt = 0.f, gl = 0.f, glvl = 0.f;
    if (tid < U) {
        cmt = cm[tid] * 6.f;
        gl = gleak[tid];
        glvl = gl * vleak[tid];
    }
    float acc_o = 0.f;
    __syncthreads();

    for (int s = 0; s < S; ++s) {
        float wn = 0.f, wd = 0.f;
        if (tid < U) {
            wn = wns[(b * S + s) * U + tid];
            wd = wds[(b * S + s) * U + tid];
        }
        for (int u = 0; u < NU; ++u) {
            float an = 0.f, ad = 0.f;
            const int i0 = p * 12;
#pragma unroll
            for (int ii = 0; ii < 12; ++ii) {
                int i = i0 + ii;
                float vi = vv[i];
                int o = i * U + j;
                float e = exp2f(fmaf(vi, A[o], Bc[o]));
                float r = 1.f / (1.f + e);
                an = fmaf(WE[o], r, an);
                ad = fmaf(WM[o], r, ad);
            }
            pn[tid] = an;
            pd[tid] = ad;
            __syncthreads();
            if (tid < U) {
                float num = fmaf(cmt, vv[tid], glvl) + wn;
                float den = cmt + gl + wd;
#pragma unroll
                for (int qq = 0; qq < P; ++qq) { num += pn[qq * U + tid]; den += pd[qq * U + tid]; }
                vv[tid] = num / (den + 1e-8f);
            }
            __syncthreads();
        }
        if (tid < 4) acc_o += vv[tid];
    }
    if (tid < 4) out4[tid] = (acc_o * 0.125f) * ow_[tid] + ob_[tid];
    __syncthreads();
    if (tid < 2) {
        float r = hb[tid];
#pragma unroll
        for (int k = 0; k < 4; ++k) r += out4[k] * hw[k * 2 + tid];
        outp[b * 2 + tid] = tanhf(r);
    }
}

// ---------------------------------------------------------------------------
extern "C" void kernel_launch(void* const* d_in, const int* in_sizes, int n_in,
                              void* d_out, int out_size, void* d_ws, size_t ws_size,
                              hipStream_t stream) {
    const float* depth  = (const float*)d_in[0];
    const float* relpos = (const float*)d_in[1];
    const float* w1 = (const float*)d_in[2];
    const float* b1 = (const float*)d_in[3];
    const float* w2 = (const float*)d_in[4];
    const float* b2 = (const float*)d_in[5];
    const float* w3 = (const float*)d_in[6];
    const float* b3 = (const float*)d_in[7];
    const float* w4 = (const float*)d_in[8];
    const float* b4 = (const float*)d_in[9];
    const float* gleak = (const float*)d_in[10];
    const float* vleak = (const float*)d_in[11];
    const float* cm    = (const float*)d_in[12];
    const float* mu    = (const float*)d_in[13];
    const float* sigma = (const float*)d_in[14];
    const float* wsyn  = (const float*)d_in[15];
    const float* erev  = (const float*)d_in[16];
    const float* mask  = (const float*)d_in[17];
    const float* smu   = (const float*)d_in[18];
    const float* ssig  = (const float*)d_in[19];
    const float* sw    = (const float*)d_in[20];
    const float* sev   = (const float*)d_in[21];
    const float* smask = (const float*)d_in[22];
    const float* iw    = (const float*)d_in[23];
    const float* ib    = (const float*)d_in[24];
    const float* ow_   = (const float*)d_in[25];
    const float* ob_   = (const float*)d_in[26];
    const float* hw    = (const float*)d_in[27];
    const float* hb    = (const float*)d_in[28];

    unsigned short* c2h = (unsigned short*)d_ws;   // 10,485,760 ush (20.97 MB)
    unsigned short* c2l = c2h + 10485760;          // 10,485,760 ush
    unsigned short* wB  = c2l + 10485760;          //    294,912 ush (conv2 B-frags)
    unsigned short* wB3 = wB + 294912;             //    147,456 ush (conv3 B-frags)
    float* conv3o = (float*)(wB3 + 147456);        //  2,621,440 f32
    float* wnsb   = conv3o + 2621440;              //     12,288
    float* wdsb   = wnsb + 12288;                  //     12,288

    k_prep_w<<<dim3(1152), dim3(256), 0, stream>>>(w2, wB, 8, 128, 294912);
    k_prep_w<<<dim3(576), dim3(256), 0, stream>>>(w3, wB3, 4, 64, 147456);

    k_conv12<<<dim3(1024), dim3(640), 0, stream>>>(depth, w1, b1, wB, b2, c2h, c2l);
    k_conv3<<<dim3(256), dim3(640), 0, stream>>>(c2h, c2l, wB3, b3, conv3o);
    k_sens4<<<dim3(256), dim3(256), 0, stream>>>(conv3o, w4, b4, relpos,
                                                 smu, ssig, sw, sev, smask,
                                                 iw, ib, wnsb, wdsb);
    k_recur<<<dim3(32), dim3(192), 0, stream>>>(wnsb, wdsb, gleak, vleak, cm, mu, sigma,
                                                wsyn, erev, mask, ow_, ob_, hw, hb,
                                                (float*)d_out);
}